// Round 6
// baseline (1022.274 us; speedup 1.0000x reference)
//
#include <hip/hip_runtime.h>

#define NTOK 16384
#define CDIM 256
#define INNER 1024
#define WW 128
#define HH 128

typedef unsigned short bf16_t;

__device__ __forceinline__ float bf2f(bf16_t u) {
    union { unsigned int i; float f; } x;
    x.i = ((unsigned int)u) << 16;
    return x.f;
}
__device__ __forceinline__ bf16_t f2bf(float f) {
    union { float f; unsigned int i; } x;
    x.f = f;
    unsigned int r = x.i + 0x7FFFu + ((x.i >> 16) & 1u);
    return (bf16_t)(r >> 16);
}

// per-batch workspace byte offsets (peak 109,322,240 B ~ 104.3 MiB)
static const size_t OFF_XN   = 0;          // bf16 [256][16384] (8.4MB) -> outc after k5
static const size_t OFF_OUTC = 0;          // bf16 [16384][256]
static const size_t OFF_Q    = 8388608;    // bf16 [1024][16384] (33.5MB) -> vp/pe1/pe2 after k2
static const size_t OFF_VP   = 8388608;    // bf16 [256][16384]
static const size_t OFF_PE1  = 16777216;   // bf16 [256][16384]
static const size_t OFF_PE2  = 25165824;   // bf16 [256][16384]
static const size_t OFF_K    = 41943040;   // bf16 [1024][16384] -> xo after k2
static const size_t OFF_XO   = 41943040;
static const size_t OFF_V    = 75497472;   // bf16 [1024][16384]
static const size_t OFF_S    = 109051904;  // f32 [16][64][64] (262144 B)
static const size_t OFF_SSQ  = 109314048;  // f32 [1024]
static const size_t OFF_SSK  = 109318144;  // f32 [1024]

// ---------------- K0: x_b [t][256] f32 -> xn [c][16384] bf16 ----------------
__global__ __launch_bounds__(256) void k0_transpose(const float* __restrict__ xb,
                                                    bf16_t* __restrict__ xnb) {
    __shared__ bf16_t tile[32][33];
    int t0 = blockIdx.x * 32;
    int c0 = blockIdx.y * 32;
    int tx = threadIdx.x & 31, ty = threadIdx.x >> 5;  // ty 0..7
#pragma unroll
    for (int l = 0; l < 4; l++) {
        int t = t0 + ty + l * 8;
        tile[ty + l * 8][tx] = f2bf(xb[(size_t)t * CDIM + c0 + tx]);
    }
    __syncthreads();
#pragma unroll
    for (int l = 0; l < 4; l++) {
        int c = c0 + ty + l * 8;
        xnb[(size_t)c * NTOK + t0 + tx] = tile[tx][ty + l * 8];
    }
}

// ---------------- K1: grouped conv3x3 + BN -> q,k,v bf16 (+ sumsq(q), sumsq(k) f32) ----------------
__global__ __launch_bounds__(256) void k1_qkv(
    const bf16_t* __restrict__ xn,
    const float* __restrict__ wq, const float* __restrict__ wk, const float* __restrict__ wv,
    const float* __restrict__ qg, const float* __restrict__ qb, const float* __restrict__ qm, const float* __restrict__ qv,
    const float* __restrict__ kg, const float* __restrict__ kb, const float* __restrict__ km, const float* __restrict__ kv_,
    const float* __restrict__ vg, const float* __restrict__ vb, const float* __restrict__ vm, const float* __restrict__ vv,
    bf16_t* __restrict__ qo, bf16_t* __restrict__ ko, bf16_t* __restrict__ vo,
    float* __restrict__ ssq, float* __restrict__ ssk) {
    int ychunk = blockIdx.x;   // 0..15
    int cin = blockIdx.y;      // 0..255
    int y0 = ychunk * 8;
    __shared__ float taps[10][130];
    __shared__ float red[4];
    const bf16_t* plane = xn + (size_t)cin * NTOK;
    for (int idx = threadIdx.x; idx < 1300; idx += 256) {
        int i = idx / 130, c = idx % 130;
        int gy = y0 - 1 + i, gx = c - 1;
        float val = 0.f;
        if (gy >= 0 && gy < HH && gx >= 0 && gx < WW) val = bf2f(plane[gy * WW + gx]);
        taps[i][c] = val;
    }
    __syncthreads();
    int x = threadIdx.x & 127;
    int half = threadIdx.x >> 7;
    int ocb = cin * 4;
#pragma unroll 1
    for (int p = 0; p < 3; p++) {
        const float* wsrc = (p == 0) ? wq : ((p == 1) ? wk : wv);
        const float* gp = (p == 0) ? qg : ((p == 1) ? kg : vg);
        const float* bp = (p == 0) ? qb : ((p == 1) ? kb : vb);
        const float* mp = (p == 0) ? qm : ((p == 1) ? km : vm);
        const float* vp_ = (p == 0) ? qv : ((p == 1) ? kv_ : vv);
        bf16_t* op = (p == 0) ? qo : ((p == 1) ? ko : vo);
        float wloc[4][9], scale[4], shift[4];
#pragma unroll
        for (int s = 0; s < 4; s++) {
            const float* wp = wsrc + (size_t)(ocb + s) * 9;
#pragma unroll
            for (int t = 0; t < 9; t++) wloc[s][t] = wp[t];
            float sc = gp[ocb + s] * rsqrtf(vp_[ocb + s] + 1e-5f);
            scale[s] = sc;
            shift[s] = bp[ocb + s] - mp[ocb + s] * sc;
        }
        float ssl[4] = {0.f, 0.f, 0.f, 0.f};
#pragma unroll
        for (int rp = 0; rp < 4; rp++) {
            int r = rp * 2 + half;
            float t00 = taps[r][x],     t01 = taps[r][x + 1],     t02 = taps[r][x + 2];
            float t10 = taps[r + 1][x], t11 = taps[r + 1][x + 1], t12 = taps[r + 1][x + 2];
            float t20 = taps[r + 2][x], t21 = taps[r + 2][x + 1], t22 = taps[r + 2][x + 2];
            size_t obase = (size_t)ocb * NTOK + (size_t)(y0 + r) * WW + x;
#pragma unroll
            for (int s = 0; s < 4; s++) {
                float acc = wloc[s][0] * t00 + wloc[s][1] * t01 + wloc[s][2] * t02
                          + wloc[s][3] * t10 + wloc[s][4] * t11 + wloc[s][5] * t12
                          + wloc[s][6] * t20 + wloc[s][7] * t21 + wloc[s][8] * t22;
                float val = acc * scale[s] + shift[s];
                op[obase + (size_t)s * NTOK] = f2bf(val);
                ssl[s] += val * val;
            }
        }
        if (p < 2) {
            float* ssdst = (p == 0) ? ssq : ssk;
#pragma unroll 1
            for (int s = 0; s < 4; s++) {
                float v = ssl[s];
#pragma unroll
                for (int o = 32; o > 0; o >>= 1) v += __shfl_down(v, o);
                if ((threadIdx.x & 63) == 0) red[threadIdx.x >> 6] = v;
                __syncthreads();
                if (threadIdx.x == 0)
                    atomicAdd(&ssdst[ocb + s], red[0] + red[1] + red[2] + red[3]);
                __syncthreads();
            }
        }
    }
}

// ---------------- K2: S[h][d][e] += sum_t k[d,t]*q[e,t] (split-K, atomics, f32 acc) ----------------
__global__ __launch_bounds__(256) void k2_sgemm(const bf16_t* __restrict__ qbuf,
                                                const bf16_t* __restrict__ kbuf,
                                                float* __restrict__ S) {
    int chunk = blockIdx.x;  // 0..31, 512 tokens each
    int h = blockIdx.y;      // 0..15
    __shared__ __align__(16) float lk[64][68];
    __shared__ __align__(16) float lq[64][68];
    const bf16_t* kg = kbuf + ((size_t)h * 64) * NTOK + (size_t)chunk * 512;
    const bf16_t* qg = qbuf + ((size_t)h * 64) * NTOK + (size_t)chunk * 512;
    int te = threadIdx.x & 15, td = threadIdx.x >> 4;  // td 0..15
    float acc[4][4];
#pragma unroll
    for (int i = 0; i < 4; i++)
#pragma unroll
        for (int j = 0; j < 4; j++) acc[i][j] = 0.f;
#pragma unroll 1
    for (int tile = 0; tile < 8; tile++) {
#pragma unroll
        for (int it = 0; it < 16; it++) {
            int row = it * 4 + (threadIdx.x >> 6);
            int col = threadIdx.x & 63;
            lk[row][col] = bf2f(kg[(size_t)row * NTOK + tile * 64 + col]);
            lq[row][col] = bf2f(qg[(size_t)row * NTOK + tile * 64 + col]);
        }
        __syncthreads();
#pragma unroll 1
        for (int tt = 0; tt < 64; tt += 4) {
            float4 av[4], bv[4];
#pragma unroll
            for (int i = 0; i < 4; i++) av[i] = *(const float4*)&lk[td + 16 * i][tt];
#pragma unroll
            for (int j = 0; j < 4; j++) bv[j] = *(const float4*)&lq[te + 16 * j][tt];
#pragma unroll
            for (int i = 0; i < 4; i++)
#pragma unroll
                for (int j = 0; j < 4; j++)
                    acc[i][j] += av[i].x * bv[j].x + av[i].y * bv[j].y +
                                 av[i].z * bv[j].z + av[i].w * bv[j].w;
        }
        __syncthreads();
    }
#pragma unroll
    for (int i = 0; i < 4; i++)
#pragma unroll
        for (int j = 0; j < 4; j++)
            atomicAdd(&S[(size_t)h * 4096 + (size_t)(td + 16 * i) * 64 + (te + 16 * j)],
                      acc[i][j]);
}

// ---------------- K3: fold norms+rescale, softmax over e, in place (f32) ----------------
__global__ __launch_bounds__(64) void k3_softmax(float* __restrict__ S,
                                                 const float* __restrict__ ssq,
                                                 const float* __restrict__ ssk,
                                                 const float* __restrict__ rescale) {
    int h = blockIdx.x;  // 0..15
    int d = threadIdx.x;
    __shared__ float rq[64];
    int cbase = h * 64;
    rq[d] = 1.0f / fmaxf(sqrtf(ssq[cbase + d]), 1e-12f);
    float rk = 1.0f / fmaxf(sqrtf(ssk[cbase + d]), 1e-12f);
    __syncthreads();
    float rsc = rescale[h];
    float* row = S + (size_t)h * 4096 + (size_t)d * 64;
    float sv[64];
    float mx = -3.4e38f;
#pragma unroll
    for (int e = 0; e < 64; e++) {
        sv[e] = row[e] * rk * rq[e] * rsc;
        mx = fmaxf(mx, sv[e]);
    }
    float sum = 0.f;
#pragma unroll
    for (int e = 0; e < 64; e++) {
        sv[e] = expf(sv[e] - mx);
        sum += sv[e];
    }
    float inv = 1.0f / sum;
#pragma unroll
    for (int e = 0; e < 64; e++) row[e] = sv[e] * inv;
}

// ---------------- K4: xo[d][t] = sum_e attn[d][e] * v[e][t] ----------------
__global__ __launch_bounds__(256) void k4_xo(const float* __restrict__ S,
                                             const bf16_t* __restrict__ vbuf,
                                             bf16_t* __restrict__ xo) {
    int tc = blockIdx.x;  // 0..63, 256 tokens each
    int h = blockIdx.y;   // 0..15
    __shared__ __align__(16) float at[64][64];
    for (int i = threadIdx.x; i < 4096; i += 256) ((float*)at)[i] = S[(size_t)h * 4096 + i];
    __syncthreads();
    int tl = threadIdx.x & 63;
    int dg = threadIdx.x >> 6;  // 0..3
    const bf16_t* vg = vbuf + ((size_t)h * 64) * NTOK + (size_t)tc * 256;
    bf16_t* xg = xo + ((size_t)h * 64) * NTOK + (size_t)tc * 256;
    float acc[16][4];
#pragma unroll
    for (int i = 0; i < 16; i++)
#pragma unroll
        for (int s = 0; s < 4; s++) acc[i][s] = 0.f;
#pragma unroll 1
    for (int eg = 0; eg < 16; eg++) {
        float ve[4][4];
#pragma unroll
        for (int eo = 0; eo < 4; eo++)
#pragma unroll
            for (int s = 0; s < 4; s++)
                ve[eo][s] = bf2f(vg[(size_t)(eg * 4 + eo) * NTOK + s * 64 + tl]);
#pragma unroll
        for (int i = 0; i < 16; i++) {
            const float4 a = *(const float4*)&at[dg * 16 + i][eg * 4];
#pragma unroll
            for (int s = 0; s < 4; s++)
                acc[i][s] += a.x * ve[0][s] + a.y * ve[1][s] + a.z * ve[2][s] + a.w * ve[3][s];
        }
    }
#pragma unroll
    for (int i = 0; i < 16; i++)
#pragma unroll
        for (int s = 0; s < 4; s++)
            xg[(size_t)(dg * 16 + i) * NTOK + s * 64 + tl] = f2bf(acc[i][s]);
}

// ---------------- K5: C[16384][256] = A[16384][1024](bf16 raw-reshape) @ W[256][1024]^T + pb ----------------
__global__ __launch_bounds__(256) void k5_outc(const bf16_t* __restrict__ A,
                                               const float* __restrict__ W,
                                               const float* __restrict__ pb,
                                               bf16_t* __restrict__ C) {
    int mb = blockIdx.x;  // 0..127, M tile 128
    int nb = blockIdx.y;  // 0..3,   N tile 64
    __shared__ __align__(16) float smem[128 * 36 + 64 * 36];
    float (*As)[36] = (float (*)[36])smem;
    float (*Ws)[36] = (float (*)[36])(smem + 128 * 36);
    int tm = threadIdx.x & 15, tn = threadIdx.x >> 4;
    float acc[8][4];
#pragma unroll
    for (int i = 0; i < 8; i++)
#pragma unroll
        for (int j = 0; j < 4; j++) acc[i][j] = 0.f;
    const bf16_t* Ab = A + (size_t)mb * 128 * 1024;
    const float* Wb = W + (size_t)nb * 64 * 1024;
#pragma unroll 1
    for (int kc = 0; kc < 32; kc++) {
#pragma unroll
        for (int l = 0; l < 4; l++) {
            int f4 = threadIdx.x + 256 * l;
            int row = f4 >> 3, col = (f4 & 7) * 4;
            ushort4 a4 = *(const ushort4*)&Ab[(size_t)row * 1024 + kc * 32 + col];
            As[row][col] = bf2f(a4.x);
            As[row][col + 1] = bf2f(a4.y);
            As[row][col + 2] = bf2f(a4.z);
            As[row][col + 3] = bf2f(a4.w);
        }
#pragma unroll
        for (int l = 0; l < 2; l++) {
            int f4 = threadIdx.x + 256 * l;
            int row = f4 >> 3, col = (f4 & 7) * 4;
            *(float4*)&Ws[row][col] = *(const float4*)&Wb[(size_t)row * 1024 + kc * 32 + col];
        }
        __syncthreads();
#pragma unroll 1
        for (int kk = 0; kk < 32; kk += 4) {
            float4 av[8], wv[4];
#pragma unroll
            for (int i = 0; i < 8; i++) av[i] = *(const float4*)&As[tm + 16 * i][kk];
#pragma unroll
            for (int j = 0; j < 4; j++) wv[j] = *(const float4*)&Ws[tn + 16 * j][kk];
#pragma unroll
            for (int i = 0; i < 8; i++)
#pragma unroll
                for (int j = 0; j < 4; j++)
                    acc[i][j] += av[i].x * wv[j].x + av[i].y * wv[j].y +
                                 av[i].z * wv[j].z + av[i].w * wv[j].w;
        }
        __syncthreads();
    }
    __syncthreads();
    bf16_t* ot = (bf16_t*)smem;  // 128 x 80 ushorts
#pragma unroll
    for (int i = 0; i < 8; i++)
#pragma unroll
        for (int j = 0; j < 4; j++) {
            int co = nb * 64 + tn + 16 * j;
            ot[(tm + 16 * i) * 80 + tn + 16 * j] = f2bf(acc[i][j] + pb[co]);
        }
    __syncthreads();
#pragma unroll
    for (int pass = 0; pass < 4; pass++) {
        int f = pass * 256 + threadIdx.x;
        int row = f >> 3, seg = f & 7;
        uint4 val = *(const uint4*)&ot[row * 80 + seg * 8];
        *(uint4*)&C[(size_t)(mb * 128 + row) * 256 + nb * 64 + seg * 8] = val;
    }
}

// ---------------- K6: vp[co][t] = sum_c W[co][c]*v[c][t] + pb[co] ----------------
__global__ __launch_bounds__(256) void k6_vp(const bf16_t* __restrict__ vbuf,
                                             const float* __restrict__ W,
                                             const float* __restrict__ pb,
                                             bf16_t* __restrict__ vp) {
    int tb = blockIdx.x;  // 0..127, 128 tokens
    int cb = blockIdx.y;  // 0..3,   64 co
    __shared__ __align__(16) float Vs[32][132];
    __shared__ __align__(16) float Ws[64][36];
    int tl = threadIdx.x & 31;
    int cg = threadIdx.x >> 5;  // 0..7
    float acc[8][4];
#pragma unroll
    for (int i = 0; i < 8; i++)
#pragma unroll
        for (int s = 0; s < 4; s++) acc[i][s] = 0.f;
    const bf16_t* vb_ = vbuf + (size_t)tb * 128;
    const float* Wb = W + (size_t)cb * 64 * 1024;
#pragma unroll 1
    for (int kc = 0; kc < 32; kc++) {
#pragma unroll
        for (int l = 0; l < 4; l++) {
            int f4 = threadIdx.x + 256 * l;
            int row = f4 >> 5, col = (f4 & 31) * 4;
            ushort4 v4 = *(const ushort4*)&vb_[(size_t)(kc * 32 + row) * NTOK + col];
            Vs[row][col] = bf2f(v4.x);
            Vs[row][col + 1] = bf2f(v4.y);
            Vs[row][col + 2] = bf2f(v4.z);
            Vs[row][col + 3] = bf2f(v4.w);
        }
#pragma unroll
        for (int l = 0; l < 2; l++) {
            int f4 = threadIdx.x + 256 * l;
            int row = f4 >> 3, col = (f4 & 7) * 4;
            *(float4*)&Ws[row][col] = *(const float4*)&Wb[(size_t)row * 1024 + kc * 32 + col];
        }
        __syncthreads();
#pragma unroll 1
        for (int cc = 0; cc < 32; cc += 4) {
            float4 wv[8];
#pragma unroll
            for (int i = 0; i < 8; i++) wv[i] = *(const float4*)&Ws[cg * 8 + i][cc];
            float4 vv0 = *(const float4*)&Vs[cc + 0][tl * 4];
            float4 vv1 = *(const float4*)&Vs[cc + 1][tl * 4];
            float4 vv2 = *(const float4*)&Vs[cc + 2][tl * 4];
            float4 vv3 = *(const float4*)&Vs[cc + 3][tl * 4];
#pragma unroll
            for (int i = 0; i < 8; i++) {
                acc[i][0] += wv[i].x * vv0.x + wv[i].y * vv1.x + wv[i].z * vv2.x + wv[i].w * vv3.x;
                acc[i][1] += wv[i].x * vv0.y + wv[i].y * vv1.y + wv[i].z * vv2.y + wv[i].w * vv3.y;
                acc[i][2] += wv[i].x * vv0.z + wv[i].y * vv1.z + wv[i].z * vv2.z + wv[i].w * vv3.z;
                acc[i][3] += wv[i].x * vv0.w + wv[i].y * vv1.w + wv[i].z * vv2.w + wv[i].w * vv3.w;
            }
        }
        __syncthreads();
    }
#pragma unroll
    for (int i = 0; i < 8; i++) {
        int co = cb * 64 + cg * 8 + i;
        float bias = pb[co];
        ushort4 r;
        r.x = f2bf(acc[i][0] + bias);
        r.y = f2bf(acc[i][1] + bias);
        r.z = f2bf(acc[i][2] + bias);
        r.w = f2bf(acc[i][3] + bias);
        *(ushort4*)&vp[(size_t)co * NTOK + (size_t)tb * 128 + tl * 4] = r;
    }
}

// ---------------- K7/K8: depthwise 3x3 conv (optional exact GELU) ----------------
__global__ __launch_bounds__(256) void k_dwconv(const bf16_t* __restrict__ in,
                                                const float* __restrict__ wt,
                                                bf16_t* __restrict__ out, int do_gelu) {
    int ychunk = blockIdx.x;  // 0..15
    int ch = blockIdx.y;      // 0..255
    int y0 = ychunk * 8;
    __shared__ float taps[10][130];
    const bf16_t* plane = in + (size_t)ch * NTOK;
    for (int idx = threadIdx.x; idx < 1300; idx += 256) {
        int i = idx / 130, c = idx % 130;
        int gy = y0 - 1 + i, gx = c - 1;
        float val = 0.f;
        if (gy >= 0 && gy < HH && gx >= 0 && gx < WW) val = bf2f(plane[gy * WW + gx]);
        taps[i][c] = val;
    }
    __syncthreads();
    float w[9];
#pragma unroll
    for (int t = 0; t < 9; t++) w[t] = wt[(size_t)ch * 9 + t];
    int x = threadIdx.x & 127;
    int half = threadIdx.x >> 7;
    bf16_t* oplane = out + (size_t)ch * NTOK;
#pragma unroll
    for (int rp = 0; rp < 4; rp++) {
        int r = rp * 2 + half;
        float acc = w[0] * taps[r][x]     + w[1] * taps[r][x + 1]     + w[2] * taps[r][x + 2]
                  + w[3] * taps[r + 1][x] + w[4] * taps[r + 1][x + 1] + w[5] * taps[r + 1][x + 2]
                  + w[6] * taps[r + 2][x] + w[7] * taps[r + 2][x + 1] + w[8] * taps[r + 2][x + 2];
        if (do_gelu) acc = 0.5f * acc * (1.0f + erff(acc * 0.70710678118654752f));
        oplane[(size_t)(y0 + r) * WW + x] = f2bf(acc);
    }
}

// ---------------- K9: out[t][c] = outc[t][c] + pe2[c][t]  -> f32 output ----------------
__global__ __launch_bounds__(256) void k9_final(const bf16_t* __restrict__ outc,
                                                const bf16_t* __restrict__ pe2,
                                                float* __restrict__ out) {
    __shared__ float tile[32][33];
    int t0 = blockIdx.x * 32;
    int c0 = blockIdx.y * 32;
    int tx = threadIdx.x & 31, ty = threadIdx.x >> 5;
#pragma unroll
    for (int l = 0; l < 4; l++) {
        int c = c0 + ty + l * 8;
        tile[ty + l * 8][tx] = bf2f(pe2[(size_t)c * NTOK + t0 + tx]);
    }
    __syncthreads();
#pragma unroll
    for (int l = 0; l < 4; l++) {
        int t = t0 + ty + l * 8;
        size_t idx = (size_t)t * CDIM + c0 + tx;
        out[idx] = bf2f(outc[idx]) + tile[tx][ty + l * 8];
    }
}

extern "C" void kernel_launch(void* const* d_in, const int* in_sizes, int n_in,
                              void* d_out, int out_size, void* d_ws, size_t ws_size,
                              hipStream_t stream) {
    const float* x_in    = (const float*)d_in[0];
    const float* wq      = (const float*)d_in[1];
    const float* wk      = (const float*)d_in[2];
    const float* wv      = (const float*)d_in[3];
    const float* qg      = (const float*)d_in[4];
    const float* qb      = (const float*)d_in[5];
    const float* qm      = (const float*)d_in[6];
    const float* qv      = (const float*)d_in[7];
    const float* kg      = (const float*)d_in[8];
    const float* kb      = (const float*)d_in[9];
    const float* km      = (const float*)d_in[10];
    const float* kv_     = (const float*)d_in[11];
    const float* vg      = (const float*)d_in[12];
    const float* vb      = (const float*)d_in[13];
    const float* vm      = (const float*)d_in[14];
    const float* vv      = (const float*)d_in[15];
    const float* rescale = (const float*)d_in[16];
    const float* proj_w  = (const float*)d_in[17];
    const float* proj_b  = (const float*)d_in[18];
    const float* pos_w1  = (const float*)d_in[19];
    const float* pos_w2  = (const float*)d_in[20];

    char* ws = (char*)d_ws;
    bf16_t* xn   = (bf16_t*)(ws + OFF_XN);
    bf16_t* q    = (bf16_t*)(ws + OFF_Q);
    bf16_t* k    = (bf16_t*)(ws + OFF_K);
    bf16_t* v    = (bf16_t*)(ws + OFF_V);
    bf16_t* xo   = (bf16_t*)(ws + OFF_XO);
    bf16_t* outc = (bf16_t*)(ws + OFF_OUTC);
    bf16_t* vp   = (bf16_t*)(ws + OFF_VP);
    bf16_t* pe1  = (bf16_t*)(ws + OFF_PE1);
    bf16_t* pe2  = (bf16_t*)(ws + OFF_PE2);
    float* S     = (float*)(ws + OFF_S);
    float* ssq   = (float*)(ws + OFF_SSQ);
    float* ssk   = (float*)(ws + OFF_SSK);

    for (int b = 0; b < 2; b++) {
        const float* xb = x_in + (size_t)b * NTOK * CDIM;
        float* outb = (float*)d_out + (size_t)b * NTOK * CDIM;
        // zero S + ssq + ssk (contiguous region, 262144 + 4096 + 4096 B)
        hipMemsetAsync(ws + OFF_S, 0, (size_t)270336, stream);
        k0_transpose<<<dim3(512, 8), 256, 0, stream>>>(xb, xn);
        k1_qkv<<<dim3(16, 256), 256, 0, stream>>>(xn, wq, wk, wv,
                                                  qg, qb, qm, qv,
                                                  kg, kb, km, kv_,
                                                  vg, vb, vm, vv,
                                                  q, k, v, ssq, ssk);
        k2_sgemm<<<dim3(32, 16), 256, 0, stream>>>(q, k, S);
        k3_softmax<<<dim3(16), 64, 0, stream>>>(S, ssq, ssk, rescale);
        k4_xo<<<dim3(64, 16), 256, 0, stream>>>(S, v, xo);
        k5_outc<<<dim3(128, 4), 256, 0, stream>>>(xo, proj_w, proj_b, outc);
        k6_vp<<<dim3(128, 4), 256, 0, stream>>>(v, proj_w, proj_b, vp);
        k_dwconv<<<dim3(16, 256), 256, 0, stream>>>(vp, pos_w1, pe1, 1);
        k_dwconv<<<dim3(16, 256), 256, 0, stream>>>(pe1, pos_w2, pe2, 0);
        k9_final<<<dim3(512, 8), 256, 0, stream>>>(outc, pe2, outb);
    }
}

// Round 7
// 521.592 us; speedup vs baseline: 1.9599x; 1.9599x over previous
//
#include <hip/hip_runtime.h>

#define NTOK 16384
#define CDIM 256
#define INNER 1024
#define WW 128
#define HH 128

typedef unsigned short bf16_t;
typedef __bf16 bf16x8 __attribute__((ext_vector_type(8)));
typedef float f32x4 __attribute__((ext_vector_type(4)));

__device__ __forceinline__ float bf2f(bf16_t u) {
    union { unsigned int i; float f; } x;
    x.i = ((unsigned int)u) << 16;
    return x.f;
}
__device__ __forceinline__ bf16_t f2bf(float f) {
    union { float f; unsigned int i; } x;
    x.f = f;
    unsigned int r = x.i + 0x7FFFu + ((x.i >> 16) & 1u);
    return (bf16_t)(r >> 16);
}

// two-batch workspace byte offsets (total 218,644,480 B — same footprint as r2, proven safe)
static const size_t OFF_XN   = 0;          // bf16 [2][256][16384] -> OUTC [2][16384][256] after k1
static const size_t OFF_OUTC = 0;
static const size_t OFF_Q    = 16777216;   // bf16 [2][1024][16384] -> VT [2][16384][1024] after k2
static const size_t OFF_VT   = 16777216;
static const size_t OFF_K    = 83886080;   // bf16 [2][1024][16384] -> XO after k2
static const size_t OFF_XO   = 83886080;
static const size_t OFF_V    = 150994944;  // bf16 [2][1024][16384] -> VP/PE1/PE2/WBF after k4+kT
static const size_t OFF_VP   = 150994944;  // bf16 [2][256][16384]
static const size_t OFF_PE1  = 167772160;  // bf16 [2][256][16384]
static const size_t OFF_PE2  = 184549376;  // bf16 [2][256][16384]
static const size_t OFF_WBF  = 201326592;  // bf16 [262144]
static const size_t OFF_S    = 218103808;  // f32 [2][16][64][64]
static const size_t OFF_SSQ  = 218628096;  // f32 [2][1024]
static const size_t OFF_SSK  = 218636288;  // f32 [2][1024]

// ---------------- K0: x [b][t][256] f32 -> xn [b][c][16384] bf16 ----------------
__global__ __launch_bounds__(256) void k0_transpose(const float* __restrict__ x,
                                                    bf16_t* __restrict__ xn) {
    __shared__ bf16_t tile[32][33];
    int b = blockIdx.z;
    const float* xb = x + (size_t)b * NTOK * CDIM;
    bf16_t* xnb = xn + (size_t)b * CDIM * NTOK;
    int t0 = blockIdx.x * 32;
    int c0 = blockIdx.y * 32;
    int tx = threadIdx.x & 31, ty = threadIdx.x >> 5;
#pragma unroll
    for (int l = 0; l < 4; l++) {
        int t = t0 + ty + l * 8;
        tile[ty + l * 8][tx] = f2bf(xb[(size_t)t * CDIM + c0 + tx]);
    }
    __syncthreads();
#pragma unroll
    for (int l = 0; l < 4; l++) {
        int c = c0 + ty + l * 8;
        xnb[(size_t)c * NTOK + t0 + tx] = tile[tx][ty + l * 8];
    }
}

// ---------------- K1: grouped conv3x3 + BN -> q,k,v bf16 (+ sumsq(q), sumsq(k) f32) ----------------
__global__ __launch_bounds__(256) void k1_qkv(
    const bf16_t* __restrict__ xn,
    const float* __restrict__ wq, const float* __restrict__ wk, const float* __restrict__ wv,
    const float* __restrict__ qg, const float* __restrict__ qb, const float* __restrict__ qm, const float* __restrict__ qv,
    const float* __restrict__ kg, const float* __restrict__ kb, const float* __restrict__ km, const float* __restrict__ kv_,
    const float* __restrict__ vg, const float* __restrict__ vb, const float* __restrict__ vm, const float* __restrict__ vv,
    bf16_t* __restrict__ qo, bf16_t* __restrict__ ko, bf16_t* __restrict__ vo,
    float* __restrict__ ssq, float* __restrict__ ssk) {
    int ychunk = blockIdx.x;   // 0..15
    int cin = blockIdx.y;      // 0..255
    int b = blockIdx.z;
    int y0 = ychunk * 8;
    __shared__ float taps[10][130];
    __shared__ float red[4];
    const bf16_t* plane = xn + ((size_t)(b * CDIM + cin)) * NTOK;
    for (int idx = threadIdx.x; idx < 1300; idx += 256) {
        int i = idx / 130, c = idx % 130;
        int gy = y0 - 1 + i, gx = c - 1;
        float val = 0.f;
        if (gy >= 0 && gy < HH && gx >= 0 && gx < WW) val = bf2f(plane[gy * WW + gx]);
        taps[i][c] = val;
    }
    __syncthreads();
    int x = threadIdx.x & 127;
    int half = threadIdx.x >> 7;
    int ocb = cin * 4;
#pragma unroll 1
    for (int p = 0; p < 3; p++) {
        const float* wsrc = (p == 0) ? wq : ((p == 1) ? wk : wv);
        const float* gp = (p == 0) ? qg : ((p == 1) ? kg : vg);
        const float* bp = (p == 0) ? qb : ((p == 1) ? kb : vb);
        const float* mp = (p == 0) ? qm : ((p == 1) ? km : vm);
        const float* vp_ = (p == 0) ? qv : ((p == 1) ? kv_ : vv);
        bf16_t* op = (p == 0) ? qo : ((p == 1) ? ko : vo);
        float wloc[4][9], scale[4], shift[4];
#pragma unroll
        for (int s = 0; s < 4; s++) {
            const float* wp = wsrc + (size_t)(ocb + s) * 9;
#pragma unroll
            for (int t = 0; t < 9; t++) wloc[s][t] = wp[t];
            float sc = gp[ocb + s] * rsqrtf(vp_[ocb + s] + 1e-5f);
            scale[s] = sc;
            shift[s] = bp[ocb + s] - mp[ocb + s] * sc;
        }
        float ssl[4] = {0.f, 0.f, 0.f, 0.f};
#pragma unroll
        for (int rp = 0; rp < 4; rp++) {
            int r = rp * 2 + half;
            float t00 = taps[r][x],     t01 = taps[r][x + 1],     t02 = taps[r][x + 2];
            float t10 = taps[r + 1][x], t11 = taps[r + 1][x + 1], t12 = taps[r + 1][x + 2];
            float t20 = taps[r + 2][x], t21 = taps[r + 2][x + 1], t22 = taps[r + 2][x + 2];
            size_t obase = (size_t)b * 16777216 + (size_t)ocb * NTOK + (size_t)(y0 + r) * WW + x;
#pragma unroll
            for (int s = 0; s < 4; s++) {
                float acc = wloc[s][0] * t00 + wloc[s][1] * t01 + wloc[s][2] * t02
                          + wloc[s][3] * t10 + wloc[s][4] * t11 + wloc[s][5] * t12
                          + wloc[s][6] * t20 + wloc[s][7] * t21 + wloc[s][8] * t22;
                float val = acc * scale[s] + shift[s];
                op[obase + (size_t)s * NTOK] = f2bf(val);
                ssl[s] += val * val;
            }
        }
        if (p < 2) {
            float* ssdst = (p == 0) ? ssq : ssk;
#pragma unroll 1
            for (int s = 0; s < 4; s++) {
                float v = ssl[s];
#pragma unroll
                for (int o = 32; o > 0; o >>= 1) v += __shfl_down(v, o);
                if ((threadIdx.x & 63) == 0) red[threadIdx.x >> 6] = v;
                __syncthreads();
                if (threadIdx.x == 0)
                    atomicAdd(&ssdst[b * INNER + ocb + s], red[0] + red[1] + red[2] + red[3]);
                __syncthreads();
            }
        }
    }
}

// ---------------- K2: S[b][h][d][e] += sum_t k[d,t]*q[e,t] (split-K, atomics) ----------------
__global__ __launch_bounds__(256) void k2_sgemm(const bf16_t* __restrict__ qbuf,
                                                const bf16_t* __restrict__ kbuf,
                                                float* __restrict__ S) {
    int chunk = blockIdx.x;  // 0..31
    int h = blockIdx.y;      // 0..15
    int b = blockIdx.z;
    __shared__ __align__(16) float lk[64][68];
    __shared__ __align__(16) float lq[64][68];
    const bf16_t* kg = kbuf + (size_t)b * 16777216 + ((size_t)h * 64) * NTOK + (size_t)chunk * 512;
    const bf16_t* qg = qbuf + (size_t)b * 16777216 + ((size_t)h * 64) * NTOK + (size_t)chunk * 512;
    int te = threadIdx.x & 15, td = threadIdx.x >> 4;
    float acc[4][4];
#pragma unroll
    for (int i = 0; i < 4; i++)
#pragma unroll
        for (int j = 0; j < 4; j++) acc[i][j] = 0.f;
#pragma unroll 1
    for (int tile = 0; tile < 8; tile++) {
#pragma unroll
        for (int it = 0; it < 16; it++) {
            int row = it * 4 + (threadIdx.x >> 6);
            int col = threadIdx.x & 63;
            lk[row][col] = bf2f(kg[(size_t)row * NTOK + tile * 64 + col]);
            lq[row][col] = bf2f(qg[(size_t)row * NTOK + tile * 64 + col]);
        }
        __syncthreads();
#pragma unroll 1
        for (int tt = 0; tt < 64; tt += 4) {
            float4 av[4], bv[4];
#pragma unroll
            for (int i = 0; i < 4; i++) av[i] = *(const float4*)&lk[td + 16 * i][tt];
#pragma unroll
            for (int j = 0; j < 4; j++) bv[j] = *(const float4*)&lq[te + 16 * j][tt];
#pragma unroll
            for (int i = 0; i < 4; i++)
#pragma unroll
                for (int j = 0; j < 4; j++)
                    acc[i][j] += av[i].x * bv[j].x + av[i].y * bv[j].y +
                                 av[i].z * bv[j].z + av[i].w * bv[j].w;
        }
        __syncthreads();
    }
    float* Sb = S + (size_t)(b * 16 + h) * 4096;
#pragma unroll
    for (int i = 0; i < 4; i++)
#pragma unroll
        for (int j = 0; j < 4; j++)
            atomicAdd(&Sb[(size_t)(td + 16 * i) * 64 + (te + 16 * j)], acc[i][j]);
}

// ---------------- K3: fold norms+rescale, softmax over e, in place (f32) ----------------
__global__ __launch_bounds__(64) void k3_softmax(float* __restrict__ S,
                                                 const float* __restrict__ ssq,
                                                 const float* __restrict__ ssk,
                                                 const float* __restrict__ rescale) {
    int bh = blockIdx.x;  // 0..31
    int b = bh >> 4, h = bh & 15;
    int d = threadIdx.x;
    __shared__ float rq[64];
    int cbase = b * INNER + h * 64;
    rq[d] = 1.0f / fmaxf(sqrtf(ssq[cbase + d]), 1e-12f);
    float rk = 1.0f / fmaxf(sqrtf(ssk[cbase + d]), 1e-12f);
    __syncthreads();
    float rsc = rescale[h];
    float* row = S + (size_t)bh * 4096 + (size_t)d * 64;
    float sv[64];
    float mx = -3.4e38f;
#pragma unroll
    for (int e = 0; e < 64; e++) {
        sv[e] = row[e] * rk * rq[e] * rsc;
        mx = fmaxf(mx, sv[e]);
    }
    float sum = 0.f;
#pragma unroll
    for (int e = 0; e < 64; e++) {
        sv[e] = expf(sv[e] - mx);
        sum += sv[e];
    }
    float inv = 1.0f / sum;
#pragma unroll
    for (int e = 0; e < 64; e++) row[e] = sv[e] * inv;
}

// ---------------- K4: xo[d][t] = sum_e attn[d][e] * v[e][t] ----------------
__global__ __launch_bounds__(256) void k4_xo(const float* __restrict__ S,
                                             const bf16_t* __restrict__ vbuf,
                                             bf16_t* __restrict__ xo) {
    int tc = blockIdx.x;  // 0..63
    int h = blockIdx.y;   // 0..15
    int b = blockIdx.z;
    __shared__ __align__(16) float at[64][64];
    for (int i = threadIdx.x; i < 4096; i += 256)
        ((float*)at)[i] = S[(size_t)(b * 16 + h) * 4096 + i];
    __syncthreads();
    int tl = threadIdx.x & 63;
    int dg = threadIdx.x >> 6;
    const bf16_t* vg = vbuf + (size_t)b * 16777216 + ((size_t)h * 64) * NTOK + (size_t)tc * 256;
    bf16_t* xg = xo + (size_t)b * 16777216 + ((size_t)h * 64) * NTOK + (size_t)tc * 256;
    float acc[16][4];
#pragma unroll
    for (int i = 0; i < 16; i++)
#pragma unroll
        for (int s = 0; s < 4; s++) acc[i][s] = 0.f;
#pragma unroll 1
    for (int eg = 0; eg < 16; eg++) {
        float ve[4][4];
#pragma unroll
        for (int eo = 0; eo < 4; eo++)
#pragma unroll
            for (int s = 0; s < 4; s++)
                ve[eo][s] = bf2f(vg[(size_t)(eg * 4 + eo) * NTOK + s * 64 + tl]);
#pragma unroll
        for (int i = 0; i < 16; i++) {
            const float4 a = *(const float4*)&at[dg * 16 + i][eg * 4];
#pragma unroll
            for (int s = 0; s < 4; s++)
                acc[i][s] += a.x * ve[0][s] + a.y * ve[1][s] + a.z * ve[2][s] + a.w * ve[3][s];
        }
    }
#pragma unroll
    for (int i = 0; i < 16; i++)
#pragma unroll
        for (int s = 0; s < 4; s++)
            xg[(size_t)(dg * 16 + i) * NTOK + s * 64 + tl] = f2bf(acc[i][s]);
}

// ---------------- KT: v [b][c][t] bf16 -> vt [b][t][c] bf16 ----------------
__global__ __launch_bounds__(256) void kT_vtrans(const bf16_t* __restrict__ v,
                                                 bf16_t* __restrict__ vt) {
    __shared__ bf16_t tile[32][33];
    int b = blockIdx.z;
    const bf16_t* in = v + (size_t)b * 16777216;
    bf16_t* out = vt + (size_t)b * 16777216;
    int t0 = blockIdx.x * 32;
    int c0 = blockIdx.y * 32;
    int tx = threadIdx.x & 31, ty = threadIdx.x >> 5;
#pragma unroll
    for (int l = 0; l < 4; l++) {
        int c = c0 + ty + l * 8;
        tile[ty + l * 8][tx] = in[(size_t)c * NTOK + t0 + tx];
    }
    __syncthreads();
#pragma unroll
    for (int l = 0; l < 4; l++) {
        int t = t0 + ty + l * 8;
        out[(size_t)t * INNER + c0 + tx] = tile[tx][ty + l * 8];
    }
}

// ---------------- CVT: proj_w f32 -> bf16 ----------------
__global__ __launch_bounds__(256) void cvt_w(const float* __restrict__ w,
                                             bf16_t* __restrict__ wbf) {
    int i = (blockIdx.x * 256 + threadIdx.x) * 4;
    float4 f = *(const float4*)&w[i];
    ushort4 r;
    r.x = f2bf(f.x); r.y = f2bf(f.y); r.z = f2bf(f.z); r.w = f2bf(f.w);
    *(ushort4*)&wbf[i] = r;
}

// ---------------- GEMM-TN (MFMA): C[m][n] = sum_k A[m][k]*B[n][k] + bias ----------------
// A,B bf16 k-major; C bf16. Tile 128x128, BK=64, 4 waves (2x2), 4x4 16x16x32 acc/wave.
__global__ __launch_bounds__(256) void gemm_tn(
    const bf16_t* __restrict__ A, const bf16_t* __restrict__ B,
    const float* __restrict__ pb, bf16_t* __restrict__ C,
    int lda, int ldb, int ldc, int K,
    long strideA, long strideB, long strideC, int bias_on_n) {
    int mb = blockIdx.x, nb = blockIdx.y, b = blockIdx.z;
    A += (size_t)b * strideA;
    B += (size_t)b * strideB;
    C += (size_t)b * strideC;
    __shared__ ushort As[128][72];
    __shared__ ushort Bs[128][72];
    int tid = threadIdx.x;
    int lane = tid & 63, wave = tid >> 6;
    int wm = wave & 1, wn = wave >> 1;
    int q = lane >> 4, l16 = lane & 15;
    f32x4 acc[4][4];
#pragma unroll
    for (int i = 0; i < 4; i++)
#pragma unroll
        for (int j = 0; j < 4; j++) acc[i][j] = (f32x4){0.f, 0.f, 0.f, 0.f};
    const bf16_t* Ab = A + (size_t)mb * 128 * lda;
    const bf16_t* Bb = B + (size_t)nb * 128 * ldb;
    int r0 = tid >> 3;        // 0..31
    int c0 = (tid & 7) * 8;   // 0..56
#pragma unroll 1
    for (int kc = 0; kc < K; kc += 64) {
#pragma unroll
        for (int l = 0; l < 4; l++) {
            int row = l * 32 + r0;
            *(uint4*)&As[row][c0] = *(const uint4*)&Ab[(size_t)row * lda + kc + c0];
            *(uint4*)&Bs[row][c0] = *(const uint4*)&Bb[(size_t)row * ldb + kc + c0];
        }
        __syncthreads();
#pragma unroll
        for (int kk = 0; kk < 64; kk += 32) {
            bf16x8 af[4], bfr[4];
#pragma unroll
            for (int i = 0; i < 4; i++)
                af[i] = *(const bf16x8*)&As[wm * 64 + i * 16 + l16][kk + q * 8];
#pragma unroll
            for (int j = 0; j < 4; j++)
                bfr[j] = *(const bf16x8*)&Bs[wn * 64 + j * 16 + l16][kk + q * 8];
#pragma unroll
            for (int i = 0; i < 4; i++)
#pragma unroll
                for (int j = 0; j < 4; j++)
                    acc[i][j] = __builtin_amdgcn_mfma_f32_16x16x32_bf16(af[i], bfr[j], acc[i][j], 0, 0, 0);
        }
        __syncthreads();
    }
    // epilogue: D layout col=lane&15, row=quad*4+reg
#pragma unroll
    for (int i = 0; i < 4; i++) {
#pragma unroll
        for (int j = 0; j < 4; j++) {
            int n = wn * 64 + j * 16 + l16;
            int gn = nb * 128 + n;
#pragma unroll
            for (int r = 0; r < 4; r++) {
                int m = wm * 64 + i * 16 + q * 4 + r;
                int gm = mb * 128 + m;
                float bias = bias_on_n ? pb[gn] : pb[gm];
                C[(size_t)gm * ldc + gn] = f2bf(acc[i][j][r] + bias);
            }
        }
    }
}

// ---------------- K7/K8: depthwise 3x3 conv (optional exact GELU) ----------------
__global__ __launch_bounds__(256) void k_dwconv(const bf16_t* __restrict__ in,
                                                const float* __restrict__ wt,
                                                bf16_t* __restrict__ out, int do_gelu) {
    int ychunk = blockIdx.x;  // 0..15
    int ch = blockIdx.y;      // 0..255
    int b = blockIdx.z;
    int y0 = ychunk * 8;
    __shared__ float taps[10][130];
    const bf16_t* plane = in + (size_t)b * 4194304 + (size_t)ch * NTOK;
    for (int idx = threadIdx.x; idx < 1300; idx += 256) {
        int i = idx / 130, c = idx % 130;
        int gy = y0 - 1 + i, gx = c - 1;
        float val = 0.f;
        if (gy >= 0 && gy < HH && gx >= 0 && gx < WW) val = bf2f(plane[gy * WW + gx]);
        taps[i][c] = val;
    }
    __syncthreads();
    float w[9];
#pragma unroll
    for (int t = 0; t < 9; t++) w[t] = wt[(size_t)ch * 9 + t];
    int x = threadIdx.x & 127;
    int half = threadIdx.x >> 7;
    bf16_t* oplane = out + (size_t)b * 4194304 + (size_t)ch * NTOK;
#pragma unroll
    for (int rp = 0; rp < 4; rp++) {
        int r = rp * 2 + half;
        float acc = w[0] * taps[r][x]     + w[1] * taps[r][x + 1]     + w[2] * taps[r][x + 2]
                  + w[3] * taps[r + 1][x] + w[4] * taps[r + 1][x + 1] + w[5] * taps[r + 1][x + 2]
                  + w[6] * taps[r + 2][x] + w[7] * taps[r + 2][x + 1] + w[8] * taps[r + 2][x + 2];
        if (do_gelu) acc = 0.5f * acc * (1.0f + erff(acc * 0.70710678118654752f));
        oplane[(size_t)(y0 + r) * WW + x] = f2bf(acc);
    }
}

// ---------------- K9: out[t][c] = outc[t][c] + pe2[c][t]  -> f32 output ----------------
__global__ __launch_bounds__(256) void k9_final(const bf16_t* __restrict__ outc,
                                                const bf16_t* __restrict__ pe2,
                                                float* __restrict__ out) {
    __shared__ float tile[32][33];
    int t0 = blockIdx.x * 32;
    int c0 = blockIdx.y * 32;
    int b = blockIdx.z;
    int tx = threadIdx.x & 31, ty = threadIdx.x >> 5;
    const bf16_t* peb = pe2 + (size_t)b * 4194304;
    const bf16_t* ob = outc + (size_t)b * 4194304;
    float* o = out + (size_t)b * 4194304;
#pragma unroll
    for (int l = 0; l < 4; l++) {
        int c = c0 + ty + l * 8;
        tile[ty + l * 8][tx] = bf2f(peb[(size_t)c * NTOK + t0 + tx]);
    }
    __syncthreads();
#pragma unroll
    for (int l = 0; l < 4; l++) {
        int t = t0 + ty + l * 8;
        size_t idx = (size_t)t * CDIM + c0 + tx;
        o[idx] = bf2f(ob[idx]) + tile[tx][ty + l * 8];
    }
}

extern "C" void kernel_launch(void* const* d_in, const int* in_sizes, int n_in,
                              void* d_out, int out_size, void* d_ws, size_t ws_size,
                              hipStream_t stream) {
    const float* x_in    = (const float*)d_in[0];
    const float* wq      = (const float*)d_in[1];
    const float* wk      = (const float*)d_in[2];
    const float* wv      = (const float*)d_in[3];
    const float* qg      = (const float*)d_in[4];
    const float* qb      = (const float*)d_in[5];
    const float* qm      = (const float*)d_in[6];
    const float* qv      = (const float*)d_in[7];
    const float* kg      = (const float*)d_in[8];
    const float* kb      = (const float*)d_in[9];
    const float* km      = (const float*)d_in[10];
    const float* kv_     = (const float*)d_in[11];
    const float* vg      = (const float*)d_in[12];
    const float* vb      = (const float*)d_in[13];
    const float* vm      = (const float*)d_in[14];
    const float* vv      = (const float*)d_in[15];
    const float* rescale = (const float*)d_in[16];
    const float* proj_w  = (const float*)d_in[17];
    const float* proj_b  = (const float*)d_in[18];
    const float* pos_w1  = (const float*)d_in[19];
    const float* pos_w2  = (const float*)d_in[20];

    char* ws = (char*)d_ws;
    bf16_t* xn   = (bf16_t*)(ws + OFF_XN);
    bf16_t* q    = (bf16_t*)(ws + OFF_Q);
    bf16_t* k    = (bf16_t*)(ws + OFF_K);
    bf16_t* v    = (bf16_t*)(ws + OFF_V);
    bf16_t* vt   = (bf16_t*)(ws + OFF_VT);
    bf16_t* xo   = (bf16_t*)(ws + OFF_XO);
    bf16_t* outc = (bf16_t*)(ws + OFF_OUTC);
    bf16_t* vp   = (bf16_t*)(ws + OFF_VP);
    bf16_t* pe1  = (bf16_t*)(ws + OFF_PE1);
    bf16_t* pe2  = (bf16_t*)(ws + OFF_PE2);
    bf16_t* wbf  = (bf16_t*)(ws + OFF_WBF);
    float* S     = (float*)(ws + OFF_S);
    float* ssq   = (float*)(ws + OFF_SSQ);
    float* ssk   = (float*)(ws + OFF_SSK);

    // zero S + ssq + ssk (contiguous, 524288 + 8192 + 8192 B)
    hipMemsetAsync(ws + OFF_S, 0, (size_t)540672, stream);

    k0_transpose<<<dim3(512, 8, 2), 256, 0, stream>>>(x_in, xn);
    k1_qkv<<<dim3(16, 256, 2), 256, 0, stream>>>(xn, wq, wk, wv,
                                                 qg, qb, qm, qv,
                                                 kg, kb, km, kv_,
                                                 vg, vb, vm, vv,
                                                 q, k, v, ssq, ssk);
    k2_sgemm<<<dim3(32, 16, 2), 256, 0, stream>>>(q, k, S);
    k3_softmax<<<dim3(32), 64, 0, stream>>>(S, ssq, ssk, rescale);
    k4_xo<<<dim3(64, 16, 2), 256, 0, stream>>>(S, v, xo);
    // v -> vt (token-major) ; q region is dead now
    kT_vtrans<<<dim3(512, 32, 2), 256, 0, stream>>>(v, vt);
    cvt_w<<<dim3(256), 256, 0, stream>>>(proj_w, wbf);
    // k5: outc[t][co] = xo_flat[t][:] . W[co][:]   (M=16384,N=256,K=1024)
    gemm_tn<<<dim3(128, 2, 2), 256, 0, stream>>>(xo, wbf, proj_b, outc,
                                                 1024, 1024, 256, 1024,
                                                 16777216L, 0L, 4194304L, 1);
    // k6: vp[co][t] = W[co][:] . vt[t][:]          (M=256,N=16384,K=1024)
    gemm_tn<<<dim3(2, 128, 2), 256, 0, stream>>>(wbf, vt, proj_b, vp,
                                                 1024, 1024, 16384, 1024,
                                                 0L, 16777216L, 4194304L, 0);
    k_dwconv<<<dim3(16, 256, 2), 256, 0, stream>>>(vp, pos_w1, pe1, 1);
    k_dwconv<<<dim3(16, 256, 2), 256, 0, stream>>>(pe1, pos_w2, pe2, 0);
    k9_final<<<dim3(512, 8, 2), 256, 0, stream>>>(outc, pe2, (float*)d_out);
}

// Round 8
// 449.525 us; speedup vs baseline: 2.2741x; 1.1603x over previous
//
#include <hip/hip_runtime.h>

#define NTOK 16384
#define CDIM 256
#define INNER 1024
#define WW 128
#define HH 128

typedef unsigned short bf16_t;
typedef __bf16 bf16x8 __attribute__((ext_vector_type(8)));
typedef float f32x4 __attribute__((ext_vector_type(4)));

__device__ __forceinline__ float bf2f(bf16_t u) {
    union { unsigned int i; float f; } x;
    x.i = ((unsigned int)u) << 16;
    return x.f;
}
__device__ __forceinline__ bf16_t f2bf(float f) {
    union { float f; unsigned int i; } x;
    x.f = f;
    unsigned int r = x.i + 0x7FFFu + ((x.i >> 16) & 1u);
    return (bf16_t)(r >> 16);
}

// two-batch workspace byte offsets (total 218,644,480 B — proven footprint)
static const size_t OFF_XN   = 0;          // bf16 [2][256][16384] -> OUTC after k1
static const size_t OFF_OUTC = 0;
static const size_t OFF_Q    = 16777216;   // bf16 [2][1024][16384] -> VT after k2
static const size_t OFF_VT   = 16777216;
static const size_t OFF_K    = 83886080;   // bf16 [2][1024][16384] -> XO after k2
static const size_t OFF_XO   = 83886080;
static const size_t OFF_V    = 150994944;  // bf16 [2][1024][16384] -> VP/PE1/PE2/WBF after kT
static const size_t OFF_VP   = 150994944;
static const size_t OFF_PE1  = 167772160;
static const size_t OFF_PE2  = 184549376;
static const size_t OFF_WBF  = 201326592;
static const size_t OFF_S    = 218103808;  // f32 [2][16][64][64]; attn bf16 in-place after k3
static const size_t OFF_SSQ  = 218628096;
static const size_t OFF_SSK  = 218636288;

// ---------------- K0: x [b][t][256] f32 -> xn [b][c][16384] bf16 ----------------
__global__ __launch_bounds__(256) void k0_transpose(const float* __restrict__ x,
                                                    bf16_t* __restrict__ xn) {
    __shared__ bf16_t tile[32][33];
    int b = blockIdx.z;
    const float* xb = x + (size_t)b * NTOK * CDIM;
    bf16_t* xnb = xn + (size_t)b * CDIM * NTOK;
    int t0 = blockIdx.x * 32;
    int c0 = blockIdx.y * 32;
    int tx = threadIdx.x & 31, ty = threadIdx.x >> 5;
#pragma unroll
    for (int l = 0; l < 4; l++) {
        int t = t0 + ty + l * 8;
        tile[ty + l * 8][tx] = f2bf(xb[(size_t)t * CDIM + c0 + tx]);
    }
    __syncthreads();
#pragma unroll
    for (int l = 0; l < 4; l++) {
        int c = c0 + ty + l * 8;
        xnb[(size_t)c * NTOK + t0 + tx] = tile[tx][ty + l * 8];
    }
}

// ---------------- K1: grouped conv3x3 + BN -> q,k,v bf16 (+ sumsq via wave atomics) ----------------
__global__ __launch_bounds__(256) void k1_qkv(
    const bf16_t* __restrict__ xn,
    const float* __restrict__ wq, const float* __restrict__ wk, const float* __restrict__ wv,
    const float* __restrict__ qg, const float* __restrict__ qb, const float* __restrict__ qm, const float* __restrict__ qv,
    const float* __restrict__ kg, const float* __restrict__ kb, const float* __restrict__ km, const float* __restrict__ kv_,
    const float* __restrict__ vg, const float* __restrict__ vb, const float* __restrict__ vm, const float* __restrict__ vv,
    bf16_t* __restrict__ qo, bf16_t* __restrict__ ko, bf16_t* __restrict__ vo,
    float* __restrict__ ssq, float* __restrict__ ssk) {
    int ychunk = blockIdx.x;   // 0..15
    int cin = blockIdx.y;      // 0..255
    int b = blockIdx.z;
    int y0 = ychunk * 8;
    __shared__ float taps[10][130];
    const bf16_t* plane = xn + ((size_t)(b * CDIM + cin)) * NTOK;
    for (int idx = threadIdx.x; idx < 1300; idx += 256) {
        int i = idx / 130, c = idx % 130;
        int gy = y0 - 1 + i, gx = c - 1;
        float val = 0.f;
        if (gy >= 0 && gy < HH && gx >= 0 && gx < WW) val = bf2f(plane[gy * WW + gx]);
        taps[i][c] = val;
    }
    __syncthreads();
    int xh = threadIdx.x & 63;   // x-pair index; full wave = one row-pair group
    int x = xh * 2;
    int qr = threadIdx.x >> 6;   // 0..3
    int ocb = cin * 4;
#pragma unroll 1
    for (int p = 0; p < 3; p++) {
        const float* wsrc = (p == 0) ? wq : ((p == 1) ? wk : wv);
        const float* gp = (p == 0) ? qg : ((p == 1) ? kg : vg);
        const float* bp = (p == 0) ? qb : ((p == 1) ? kb : vb);
        const float* mp = (p == 0) ? qm : ((p == 1) ? km : vm);
        const float* vp_ = (p == 0) ? qv : ((p == 1) ? kv_ : vv);
        bf16_t* op = (p == 0) ? qo : ((p == 1) ? ko : vo);
        float wloc[4][9], scale[4], shift[4];
#pragma unroll
        for (int s = 0; s < 4; s++) {
            const float* wp = wsrc + (size_t)(ocb + s) * 9;
#pragma unroll
            for (int t = 0; t < 9; t++) wloc[s][t] = wp[t];
            float sc = gp[ocb + s] * rsqrtf(vp_[ocb + s] + 1e-5f);
            scale[s] = sc;
            shift[s] = bp[ocb + s] - mp[ocb + s] * sc;
        }
        float ssl[4] = {0.f, 0.f, 0.f, 0.f};
#pragma unroll
        for (int rp = 0; rp < 2; rp++) {
            int r = qr * 2 + rp;
            float t0[4], t1[4], t2[4];
#pragma unroll
            for (int c = 0; c < 4; c++) {
                t0[c] = taps[r][x + c];
                t1[c] = taps[r + 1][x + c];
                t2[c] = taps[r + 2][x + c];
            }
            size_t obase = (size_t)b * 16777216 + (size_t)ocb * NTOK + (size_t)(y0 + r) * WW + x;
#pragma unroll
            for (int s = 0; s < 4; s++) {
                float a0 = wloc[s][0] * t0[0] + wloc[s][1] * t0[1] + wloc[s][2] * t0[2]
                         + wloc[s][3] * t1[0] + wloc[s][4] * t1[1] + wloc[s][5] * t1[2]
                         + wloc[s][6] * t2[0] + wloc[s][7] * t2[1] + wloc[s][8] * t2[2];
                float a1 = wloc[s][0] * t0[1] + wloc[s][1] * t0[2] + wloc[s][2] * t0[3]
                         + wloc[s][3] * t1[1] + wloc[s][4] * t1[2] + wloc[s][5] * t1[3]
                         + wloc[s][6] * t2[1] + wloc[s][7] * t2[2] + wloc[s][8] * t2[3];
                float v0 = a0 * scale[s] + shift[s];
                float v1 = a1 * scale[s] + shift[s];
                ushort2 st;
                st.x = f2bf(v0);
                st.y = f2bf(v1);
                *(ushort2*)&op[obase + (size_t)s * NTOK] = st;
                ssl[s] += v0 * v0 + v1 * v1;
            }
        }
        if (p < 2) {
            float* ssdst = (p == 0) ? ssq : ssk;
#pragma unroll
            for (int s = 0; s < 4; s++) {
                float v = ssl[s];
#pragma unroll
                for (int o = 32; o > 0; o >>= 1) v += __shfl_down(v, o, 64);
                if (xh == 0) atomicAdd(&ssdst[b * INNER + ocb + s], v);
            }
        }
    }
}

// ---------------- K2 (MFMA): S[bh][d][e] += sum_t k[d,t]*q[e,t], split-K atomics ----------------
__global__ __launch_bounds__(256) void k2_mfma(const bf16_t* __restrict__ qbuf,
                                               const bf16_t* __restrict__ kbuf,
                                               float* __restrict__ S) {
    int chunk = blockIdx.x;  // 0..7, K=2048 each
    int h = blockIdx.y;      // 0..15
    int b = blockIdx.z;
    __shared__ ushort Ks[64][72];
    __shared__ ushort Qs[64][72];
    const bf16_t* kg = kbuf + (size_t)b * 16777216 + (size_t)(h * 64) * NTOK + (size_t)chunk * 2048;
    const bf16_t* qg = qbuf + (size_t)b * 16777216 + (size_t)(h * 64) * NTOK + (size_t)chunk * 2048;
    int tid = threadIdx.x, lane = tid & 63, wave = tid >> 6;
    int wm = wave & 1, wn = wave >> 1;
    int qd = lane >> 4, l16 = lane & 15;
    int r0 = tid >> 3, c0 = (tid & 7) * 8;
    f32x4 acc[2][2];
#pragma unroll
    for (int i = 0; i < 2; i++)
#pragma unroll
        for (int j = 0; j < 2; j++) acc[i][j] = (f32x4){0.f, 0.f, 0.f, 0.f};
#pragma unroll 1
    for (int kc = 0; kc < 2048; kc += 64) {
#pragma unroll
        for (int l = 0; l < 2; l++) {
            int row = r0 + l * 32;
            *(uint4*)&Ks[row][c0] = *(const uint4*)&kg[(size_t)row * NTOK + kc + c0];
            *(uint4*)&Qs[row][c0] = *(const uint4*)&qg[(size_t)row * NTOK + kc + c0];
        }
        __syncthreads();
#pragma unroll
        for (int kk = 0; kk < 64; kk += 32) {
            bf16x8 af[2], bfr[2];
#pragma unroll
            for (int i = 0; i < 2; i++)
                af[i] = *(const bf16x8*)&Ks[wm * 32 + i * 16 + l16][kk + qd * 8];
#pragma unroll
            for (int j = 0; j < 2; j++)
                bfr[j] = *(const bf16x8*)&Qs[wn * 32 + j * 16 + l16][kk + qd * 8];
#pragma unroll
            for (int i = 0; i < 2; i++)
#pragma unroll
                for (int j = 0; j < 2; j++)
                    acc[i][j] = __builtin_amdgcn_mfma_f32_16x16x32_bf16(af[i], bfr[j], acc[i][j], 0, 0, 0);
        }
        __syncthreads();
    }
    float* Sb = S + (size_t)(b * 16 + h) * 4096;
#pragma unroll
    for (int i = 0; i < 2; i++)
#pragma unroll
        for (int j = 0; j < 2; j++)
#pragma unroll
            for (int r = 0; r < 4; r++) {
                int d = wm * 32 + i * 16 + qd * 4 + r;
                int e = wn * 32 + j * 16 + l16;
                atomicAdd(&Sb[(size_t)d * 64 + e], acc[i][j][r]);
            }
}

// ---------------- K3: fold norms+rescale, softmax, write bf16 attn IN PLACE over S ----------------
__global__ __launch_bounds__(64) void k3_softmax(float* __restrict__ S,
                                                 const float* __restrict__ ssq,
                                                 const float* __restrict__ ssk,
                                                 const float* __restrict__ rescale) {
    int bh = blockIdx.x;  // 0..31
    int b = bh >> 4, h = bh & 15;
    int d = threadIdx.x;
    __shared__ float rq[64];
    int cbase = b * INNER + h * 64;
    rq[d] = 1.0f / fmaxf(sqrtf(ssq[cbase + d]), 1e-12f);
    float rk = 1.0f / fmaxf(sqrtf(ssk[cbase + d]), 1e-12f);
    __syncthreads();
    float rsc = rescale[h];
    const float* row = S + (size_t)bh * 4096 + (size_t)d * 64;
    float sv[64];
    float mx = -3.4e38f;
#pragma unroll
    for (int e = 0; e < 64; e++) {
        sv[e] = row[e] * rk * rq[e] * rsc;
        mx = fmaxf(mx, sv[e]);
    }
    float sum = 0.f;
#pragma unroll
    for (int e = 0; e < 64; e++) {
        sv[e] = expf(sv[e] - mx);
        sum += sv[e];
    }
    float inv = 1.0f / sum;
    __syncthreads();  // all reads of S[bh] complete before bf16 overwrite
    ushort* attn = (ushort*)((char*)S + (size_t)bh * 16384);
#pragma unroll
    for (int e = 0; e < 64; e++) attn[d * 64 + e] = f2bf(sv[e] * inv);
}

// ---------------- KT: v [b][c][t] bf16 -> vt [b][t][c] bf16 ----------------
__global__ __launch_bounds__(256) void kT_vtrans(const bf16_t* __restrict__ v,
                                                 bf16_t* __restrict__ vt) {
    __shared__ bf16_t tile[32][33];
    int b = blockIdx.z;
    const bf16_t* in = v + (size_t)b * 16777216;
    bf16_t* out = vt + (size_t)b * 16777216;
    int t0 = blockIdx.x * 32;
    int c0 = blockIdx.y * 32;
    int tx = threadIdx.x & 31, ty = threadIdx.x >> 5;
#pragma unroll
    for (int l = 0; l < 4; l++) {
        int c = c0 + ty + l * 8;
        tile[ty + l * 8][tx] = in[(size_t)c * NTOK + t0 + tx];
    }
    __syncthreads();
#pragma unroll
    for (int l = 0; l < 4; l++) {
        int t = t0 + ty + l * 8;
        out[(size_t)t * INNER + c0 + tx] = tile[tx][ty + l * 8];
    }
}

// ---------------- CVT: proj_w f32 -> bf16 ----------------
__global__ __launch_bounds__(256) void cvt_w(const float* __restrict__ w,
                                             bf16_t* __restrict__ wbf) {
    int i = (blockIdx.x * 256 + threadIdx.x) * 4;
    float4 f = *(const float4*)&w[i];
    ushort4 r;
    r.x = f2bf(f.x); r.y = f2bf(f.y); r.z = f2bf(f.z); r.w = f2bf(f.w);
    *(ushort4*)&wbf[i] = r;
}

// ---------------- K4 (MFMA): xo[d][t] = sum_e attn[d][e] * vt[t][h*64+e] ----------------
__global__ __launch_bounds__(256) void k4_mfma(const float* __restrict__ Sbase,
                                               const bf16_t* __restrict__ vt,
                                               bf16_t* __restrict__ xo) {
    int tt = blockIdx.x;  // 0..127 (128-token tiles)
    int h = blockIdx.y;   // 0..15
    int b = blockIdx.z;
    int bh = b * 16 + h;
    const ushort* attn = (const ushort*)((const char*)Sbase + (size_t)bh * 16384);
    __shared__ ushort As[64][72];
    __shared__ ushort Bs[128][72];
    int tid = threadIdx.x, lane = tid & 63, wave = tid >> 6;
    int wm = wave & 1, wn = wave >> 1;
    int qd = lane >> 4, l16 = lane & 15;
    int r0 = tid >> 3, c0 = (tid & 7) * 8;
#pragma unroll
    for (int l = 0; l < 2; l++) {
        int row = r0 + l * 32;
        *(uint4*)&As[row][c0] = *(const uint4*)&attn[row * 64 + c0];
    }
    const bf16_t* vtb = vt + (size_t)b * 16777216 + (size_t)(tt * 128) * 1024 + h * 64;
#pragma unroll
    for (int l = 0; l < 4; l++) {
        int row = r0 + l * 32;
        *(uint4*)&Bs[row][c0] = *(const uint4*)&vtb[(size_t)row * 1024 + c0];
    }
    __syncthreads();
    f32x4 acc[2][4];
#pragma unroll
    for (int i = 0; i < 2; i++)
#pragma unroll
        for (int j = 0; j < 4; j++) acc[i][j] = (f32x4){0.f, 0.f, 0.f, 0.f};
#pragma unroll
    for (int kk = 0; kk < 64; kk += 32) {
        bf16x8 af[2], bfr[4];
#pragma unroll
        for (int i = 0; i < 2; i++)
            af[i] = *(const bf16x8*)&As[wm * 32 + i * 16 + l16][kk + qd * 8];
#pragma unroll
        for (int j = 0; j < 4; j++)
            bfr[j] = *(const bf16x8*)&Bs[wn * 64 + j * 16 + l16][kk + qd * 8];
#pragma unroll
        for (int i = 0; i < 2; i++)
#pragma unroll
            for (int j = 0; j < 4; j++)
                acc[i][j] = __builtin_amdgcn_mfma_f32_16x16x32_bf16(af[i], bfr[j], acc[i][j], 0, 0, 0);
    }
    bf16_t* xob = xo + (size_t)b * 16777216 + (size_t)(h * 64) * NTOK + (size_t)tt * 128;
#pragma unroll
    for (int i = 0; i < 2; i++)
#pragma unroll
        for (int j = 0; j < 4; j++)
#pragma unroll
            for (int r = 0; r < 4; r++) {
                int d = wm * 32 + i * 16 + qd * 4 + r;
                int t = wn * 64 + j * 16 + l16;
                xob[(size_t)d * NTOK + t] = f2bf(acc[i][j][r]);
            }
}

// ---------------- GEMM-TN (MFMA): C[m][n] = sum_k A[m][k]*B[n][k] + bias ----------------
__global__ __launch_bounds__(256) void gemm_tn(
    const bf16_t* __restrict__ A, const bf16_t* __restrict__ B,
    const float* __restrict__ pb, bf16_t* __restrict__ C,
    int lda, int ldb, int ldc, int K,
    long strideA, long strideB, long strideC, int bias_on_n) {
    int mb = blockIdx.x, nb = blockIdx.y, b = blockIdx.z;
    A += (size_t)b * strideA;
    B += (size_t)b * strideB;
    C += (size_t)b * strideC;
    __shared__ ushort As[128][72];
    __shared__ ushort Bs[128][72];
    int tid = threadIdx.x;
    int lane = tid & 63, wave = tid >> 6;
    int wm = wave & 1, wn = wave >> 1;
    int q = lane >> 4, l16 = lane & 15;
    f32x4 acc[4][4];
#pragma unroll
    for (int i = 0; i < 4; i++)
#pragma unroll
        for (int j = 0; j < 4; j++) acc[i][j] = (f32x4){0.f, 0.f, 0.f, 0.f};
    const bf16_t* Ab = A + (size_t)mb * 128 * lda;
    const bf16_t* Bb = B + (size_t)nb * 128 * ldb;
    int r0 = tid >> 3;
    int c0 = (tid & 7) * 8;
#pragma unroll 1
    for (int kc = 0; kc < K; kc += 64) {
#pragma unroll
        for (int l = 0; l < 4; l++) {
            int row = l * 32 + r0;
            *(uint4*)&As[row][c0] = *(const uint4*)&Ab[(size_t)row * lda + kc + c0];
            *(uint4*)&Bs[row][c0] = *(const uint4*)&Bb[(size_t)row * ldb + kc + c0];
        }
        __syncthreads();
#pragma unroll
        for (int kk = 0; kk < 64; kk += 32) {
            bf16x8 af[4], bfr[4];
#pragma unroll
            for (int i = 0; i < 4; i++)
                af[i] = *(const bf16x8*)&As[wm * 64 + i * 16 + l16][kk + q * 8];
#pragma unroll
            for (int j = 0; j < 4; j++)
                bfr[j] = *(const bf16x8*)&Bs[wn * 64 + j * 16 + l16][kk + q * 8];
#pragma unroll
            for (int i = 0; i < 4; i++)
#pragma unroll
                for (int j = 0; j < 4; j++)
                    acc[i][j] = __builtin_amdgcn_mfma_f32_16x16x32_bf16(af[i], bfr[j], acc[i][j], 0, 0, 0);
        }
        __syncthreads();
    }
#pragma unroll
    for (int i = 0; i < 4; i++) {
#pragma unroll
        for (int j = 0; j < 4; j++) {
            int n = wn * 64 + j * 16 + l16;
            int gn = nb * 128 + n;
#pragma unroll
            for (int r = 0; r < 4; r++) {
                int m = wm * 64 + i * 16 + q * 4 + r;
                int gm = mb * 128 + m;
                float bias = bias_on_n ? pb[gn] : pb[gm];
                C[(size_t)gm * ldc + gn] = f2bf(acc[i][j][r] + bias);
            }
        }
    }
}

// ---------------- K7/K8: depthwise 3x3 conv (optional exact GELU) ----------------
__global__ __launch_bounds__(256) void k_dwconv(const bf16_t* __restrict__ in,
                                                const float* __restrict__ wt,
                                                bf16_t* __restrict__ out, int do_gelu) {
    int ychunk = blockIdx.x;  // 0..15
    int ch = blockIdx.y;      // 0..255
    int b = blockIdx.z;
    int y0 = ychunk * 8;
    __shared__ float taps[10][130];
    const bf16_t* plane = in + (size_t)b * 4194304 + (size_t)ch * NTOK;
    for (int idx = threadIdx.x; idx < 1300; idx += 256) {
        int i = idx / 130, c = idx % 130;
        int gy = y0 - 1 + i, gx = c - 1;
        float val = 0.f;
        if (gy >= 0 && gy < HH && gx >= 0 && gx < WW) val = bf2f(plane[gy * WW + gx]);
        taps[i][c] = val;
    }
    __syncthreads();
    float w[9];
#pragma unroll
    for (int t = 0; t < 9; t++) w[t] = wt[(size_t)ch * 9 + t];
    int x = threadIdx.x & 127;
    int half = threadIdx.x >> 7;
    bf16_t* oplane = out + (size_t)b * 4194304 + (size_t)ch * NTOK;
#pragma unroll
    for (int rp = 0; rp < 4; rp++) {
        int r = rp * 2 + half;
        float acc = w[0] * taps[r][x]     + w[1] * taps[r][x + 1]     + w[2] * taps[r][x + 2]
                  + w[3] * taps[r + 1][x] + w[4] * taps[r + 1][x + 1] + w[5] * taps[r + 1][x + 2]
                  + w[6] * taps[r + 2][x] + w[7] * taps[r + 2][x + 1] + w[8] * taps[r + 2][x + 2];
        if (do_gelu) acc = 0.5f * acc * (1.0f + erff(acc * 0.70710678118654752f));
        oplane[(size_t)(y0 + r) * WW + x] = f2bf(acc);
    }
}

// ---------------- K9: out[t][c] = outc[t][c] + pe2[c][t]  -> f32 output ----------------
__global__ __launch_bounds__(256) void k9_final(const bf16_t* __restrict__ outc,
                                                const bf16_t* __restrict__ pe2,
                                                float* __restrict__ out) {
    __shared__ float tile[32][33];
    int t0 = blockIdx.x * 32;
    int c0 = blockIdx.y * 32;
    int b = blockIdx.z;
    int tx = threadIdx.x & 31, ty = threadIdx.x >> 5;
    const bf16_t* peb = pe2 + (size_t)b * 4194304;
    const bf16_t* ob = outc + (size_t)b * 4194304;
    float* o = out + (size_t)b * 4194304;
#pragma unroll
    for (int l = 0; l < 4; l++) {
        int c = c0 + ty + l * 8;
        tile[ty + l * 8][tx] = bf2f(peb[(size_t)c * NTOK + t0 + tx]);
    }
    __syncthreads();
#pragma unroll
    for (int l = 0; l < 4; l++) {
        int t = t0 + ty + l * 8;
        size_t idx = (size_t)t * CDIM + c0 + tx;
        o[idx] = bf2f(ob[idx]) + tile[tx][ty + l * 8];
    }
}

extern "C" void kernel_launch(void* const* d_in, const int* in_sizes, int n_in,
                              void* d_out, int out_size, void* d_ws, size_t ws_size,
                              hipStream_t stream) {
    const float* x_in    = (const float*)d_in[0];
    const float* wq      = (const float*)d_in[1];
    const float* wk      = (const float*)d_in[2];
    const float* wv      = (const float*)d_in[3];
    const float* qg      = (const float*)d_in[4];
    const float* qb      = (const float*)d_in[5];
    const float* qm      = (const float*)d_in[6];
    const float* qv      = (const float*)d_in[7];
    const float* kg      = (const float*)d_in[8];
    const float* kb      = (const float*)d_in[9];
    const float* km      = (const float*)d_in[10];
    const float* kv_     = (const float*)d_in[11];
    const float* vg      = (const float*)d_in[12];
    const float* vb      = (const float*)d_in[13];
    const float* vm      = (const float*)d_in[14];
    const float* vv      = (const float*)d_in[15];
    const float* rescale = (const float*)d_in[16];
    const float* proj_w  = (const float*)d_in[17];
    const float* proj_b  = (const float*)d_in[18];
    const float* pos_w1  = (const float*)d_in[19];
    const float* pos_w2  = (const float*)d_in[20];

    char* ws = (char*)d_ws;
    bf16_t* xn   = (bf16_t*)(ws + OFF_XN);
    bf16_t* q    = (bf16_t*)(ws + OFF_Q);
    bf16_t* k    = (bf16_t*)(ws + OFF_K);
    bf16_t* v    = (bf16_t*)(ws + OFF_V);
    bf16_t* vt   = (bf16_t*)(ws + OFF_VT);
    bf16_t* xo   = (bf16_t*)(ws + OFF_XO);
    bf16_t* outc = (bf16_t*)(ws + OFF_OUTC);
    bf16_t* vp   = (bf16_t*)(ws + OFF_VP);
    bf16_t* pe1  = (bf16_t*)(ws + OFF_PE1);
    bf16_t* pe2  = (bf16_t*)(ws + OFF_PE2);
    bf16_t* wbf  = (bf16_t*)(ws + OFF_WBF);
    float* S     = (float*)(ws + OFF_S);
    float* ssq   = (float*)(ws + OFF_SSQ);
    float* ssk   = (float*)(ws + OFF_SSK);

    hipMemsetAsync(ws + OFF_S, 0, (size_t)540672, stream);

    k0_transpose<<<dim3(512, 8, 2), 256, 0, stream>>>(x_in, xn);
    k1_qkv<<<dim3(16, 256, 2), 256, 0, stream>>>(xn, wq, wk, wv,
                                                 qg, qb, qm, qv,
                                                 kg, kb, km, kv_,
                                                 vg, vb, vm, vv,
                                                 q, k, v, ssq, ssk);
    k2_mfma<<<dim3(8, 16, 2), 256, 0, stream>>>(q, k, S);
    k3_softmax<<<dim3(32), 64, 0, stream>>>(S, ssq, ssk, rescale);
    kT_vtrans<<<dim3(512, 32, 2), 256, 0, stream>>>(v, vt);   // q dead -> vt in B
    cvt_w<<<dim3(256), 256, 0, stream>>>(proj_w, wbf);        // v dead -> wbf in D tail
    k4_mfma<<<dim3(128, 16, 2), 256, 0, stream>>>(S, vt, xo); // k dead -> xo in C
    // k5: outc[t][co] = xo_flat[t][:] . W[co][:]   (M=16384,N=256,K=1024)
    gemm_tn<<<dim3(128, 2, 2), 256, 0, stream>>>(xo, wbf, proj_b, outc,
                                                 1024, 1024, 256, 1024,
                                                 16777216L, 0L, 4194304L, 1);
    // k6: vp[co][t] = W[co][:] . vt[t][:]          (M=256,N=16384,K=1024)
    gemm_tn<<<dim3(2, 128, 2), 256, 0, stream>>>(wbf, vt, proj_b, vp,
                                                 1024, 1024, 16384, 1024,
                                                 0L, 16777216L, 4194304L, 0);
    k_dwconv<<<dim3(16, 256, 2), 256, 0, stream>>>(vp, pos_w1, pe1, 1);
    k_dwconv<<<dim3(16, 256, 2), 256, 0, stream>>>(pe1, pos_w2, pe2, 0);
    k9_final<<<dim3(512, 8, 2), 256, 0, stream>>>(outc, pe2, (float*)d_out);
}

// Round 9
// 428.918 us; speedup vs baseline: 2.3834x; 1.0480x over previous
//
#include <hip/hip_runtime.h>

#define NTOK 16384
#define CDIM 256
#define INNER 1024
#define WW 128
#define HH 128

typedef unsigned short bf16_t;
typedef __bf16 bf16x8 __attribute__((ext_vector_type(8)));
typedef float f32x4 __attribute__((ext_vector_type(4)));

__device__ __forceinline__ float bf2f(bf16_t u) {
    union { unsigned int i; float f; } x;
    x.i = ((unsigned int)u) << 16;
    return x.f;
}
__device__ __forceinline__ bf16_t f2bf(float f) {
    union { float f; unsigned int i; } x;
    x.f = f;
    unsigned int r = x.i + 0x7FFFu + ((x.i >> 16) & 1u);
    return (bf16_t)(r >> 16);
}

// two-batch workspace byte offsets (total 218,644,480 B — proven footprint)
static const size_t OFF_XN   = 0;          // bf16 [2][256][16384] -> OUTC after k1
static const size_t OFF_OUTC = 0;
static const size_t OFF_Q    = 16777216;   // bf16 [2][1024][16384] -> VT after k2
static const size_t OFF_VT   = 16777216;
static const size_t OFF_K    = 83886080;   // bf16 [2][1024][16384] -> XO after k2
static const size_t OFF_XO   = 83886080;
static const size_t OFF_V    = 150994944;  // bf16 [2][1024][16384] -> VP/PE2/WBF after kT
static const size_t OFF_VP   = 150994944;
static const size_t OFF_PE2  = 184549376;
static const size_t OFF_WBF  = 201326592;
static const size_t OFF_S    = 218103808;  // f32 [2][16][64][64]; attn bf16 in-place after k3
static const size_t OFF_SSQ  = 218628096;
static const size_t OFF_SSK  = 218636288;

// ---------------- K0: x [b][t][256] f32 -> xn [b][c][16384] bf16 ----------------
__global__ __launch_bounds__(256) void k0_transpose(const float* __restrict__ x,
                                                    bf16_t* __restrict__ xn) {
    __shared__ bf16_t tile[32][33];
    int b = blockIdx.z;
    const float* xb = x + (size_t)b * NTOK * CDIM;
    bf16_t* xnb = xn + (size_t)b * CDIM * NTOK;
    int t0 = blockIdx.x * 32;
    int c0 = blockIdx.y * 32;
    int tx = threadIdx.x & 31, ty = threadIdx.x >> 5;
#pragma unroll
    for (int l = 0; l < 4; l++) {
        int t = t0 + ty + l * 8;
        tile[ty + l * 8][tx] = f2bf(xb[(size_t)t * CDIM + c0 + tx]);
    }
    __syncthreads();
#pragma unroll
    for (int l = 0; l < 4; l++) {
        int c = c0 + ty + l * 8;
        xnb[(size_t)c * NTOK + t0 + tx] = tile[tx][ty + l * 8];
    }
}

// ---------------- K1: grouped conv3x3 + BN -> q,k,v bf16 (register tap window) ----------------
__global__ __launch_bounds__(256) void k1_qkv(
    const bf16_t* __restrict__ xn,
    const float* __restrict__ wq, const float* __restrict__ wk, const float* __restrict__ wv,
    const float* __restrict__ qg, const float* __restrict__ qb, const float* __restrict__ qm, const float* __restrict__ qv,
    const float* __restrict__ kg, const float* __restrict__ kb, const float* __restrict__ km, const float* __restrict__ kv_,
    const float* __restrict__ vg, const float* __restrict__ vb, const float* __restrict__ vm, const float* __restrict__ vv,
    bf16_t* __restrict__ qo, bf16_t* __restrict__ ko, bf16_t* __restrict__ vo,
    float* __restrict__ ssq, float* __restrict__ ssk) {
    int ychunk = blockIdx.x;   // 0..15
    int cin = blockIdx.y;      // 0..255
    int b = blockIdx.z;
    int y0 = ychunk * 8;
    __shared__ float taps[10][130];
    const bf16_t* plane = xn + ((size_t)(b * CDIM + cin)) * NTOK;
    for (int idx = threadIdx.x; idx < 1300; idx += 256) {
        int i = idx / 130, c = idx % 130;
        int gy = y0 - 1 + i, gx = c - 1;
        float val = 0.f;
        if (gy >= 0 && gy < HH && gx >= 0 && gx < WW) val = bf2f(plane[gy * WW + gx]);
        taps[i][c] = val;
    }
    __syncthreads();
    int xh = threadIdx.x & 63;   // x-pair index
    int x = xh * 2;
    int qr = threadIdx.x >> 6;   // row-pair group 0..3
    int ocb = cin * 4;
    // register tap window: rows 2qr..2qr+3, cols x..x+3 (all 16 loads batched)
    float t[4][4];
#pragma unroll
    for (int i = 0; i < 4; i++)
#pragma unroll
        for (int c = 0; c < 4; c++) t[i][c] = taps[2 * qr + i][x + c];
    size_t obase0 = (size_t)b * 16777216 + (size_t)ocb * NTOK + (size_t)(y0 + 2 * qr) * WW + x;
#pragma unroll 1
    for (int p = 0; p < 3; p++) {
        const float* wsrc = (p == 0) ? wq : ((p == 1) ? wk : wv);
        const float* gp = (p == 0) ? qg : ((p == 1) ? kg : vg);
        const float* bp = (p == 0) ? qb : ((p == 1) ? kb : vb);
        const float* mp = (p == 0) ? qm : ((p == 1) ? km : vm);
        const float* vp_ = (p == 0) ? qv : ((p == 1) ? kv_ : vv);
        bf16_t* op = (p == 0) ? qo : ((p == 1) ? ko : vo);
        float ssl[4];
#pragma unroll
        for (int s = 0; s < 4; s++) {
            const float* w = wsrc + (size_t)(ocb + s) * 9;
            float w0 = w[0], w1 = w[1], w2 = w[2], w3 = w[3], w4 = w[4],
                  w5 = w[5], w6 = w[6], w7 = w[7], w8 = w[8];
            float sc = gp[ocb + s] * rsqrtf(vp_[ocb + s] + 1e-5f);
            float sh = bp[ocb + s] - mp[ocb + s] * sc;
            float a0 = w0*t[0][0] + w1*t[0][1] + w2*t[0][2]
                     + w3*t[1][0] + w4*t[1][1] + w5*t[1][2]
                     + w6*t[2][0] + w7*t[2][1] + w8*t[2][2];
            float a1 = w0*t[0][1] + w1*t[0][2] + w2*t[0][3]
                     + w3*t[1][1] + w4*t[1][2] + w5*t[1][3]
                     + w6*t[2][1] + w7*t[2][2] + w8*t[2][3];
            float b0 = w0*t[1][0] + w1*t[1][1] + w2*t[1][2]
                     + w3*t[2][0] + w4*t[2][1] + w5*t[2][2]
                     + w6*t[3][0] + w7*t[3][1] + w8*t[3][2];
            float b1 = w0*t[1][1] + w1*t[1][2] + w2*t[1][3]
                     + w3*t[2][1] + w4*t[2][2] + w5*t[2][3]
                     + w6*t[3][1] + w7*t[3][2] + w8*t[3][3];
            a0 = a0 * sc + sh; a1 = a1 * sc + sh;
            b0 = b0 * sc + sh; b1 = b1 * sc + sh;
            ushort2 st0; st0.x = f2bf(a0); st0.y = f2bf(a1);
            ushort2 st1; st1.x = f2bf(b0); st1.y = f2bf(b1);
            *(ushort2*)&op[obase0 + (size_t)s * NTOK] = st0;
            *(ushort2*)&op[obase0 + (size_t)s * NTOK + WW] = st1;
            ssl[s] = a0 * a0 + a1 * a1 + b0 * b0 + b1 * b1;
        }
        if (p < 2) {
            float* ssdst = (p == 0) ? ssq : ssk;
#pragma unroll
            for (int s = 0; s < 4; s++) {
                float v = ssl[s];
#pragma unroll
                for (int o = 32; o > 0; o >>= 1) v += __shfl_down(v, o, 64);
                if (xh == 0) atomicAdd(&ssdst[b * INNER + ocb + s], v);
            }
        }
    }
}

// ---------------- K2 (MFMA): S[bh][d][e] += sum_t k[d,t]*q[e,t], split-K atomics ----------------
__global__ __launch_bounds__(256) void k2_mfma(const bf16_t* __restrict__ qbuf,
                                               const bf16_t* __restrict__ kbuf,
                                               float* __restrict__ S) {
    int chunk = blockIdx.x;  // 0..15, K=1024 each
    int h = blockIdx.y;      // 0..15
    int b = blockIdx.z;
    __shared__ ushort Ks[64][72];
    __shared__ ushort Qs[64][72];
    const bf16_t* kg = kbuf + (size_t)b * 16777216 + (size_t)(h * 64) * NTOK + (size_t)chunk * 1024;
    const bf16_t* qg = qbuf + (size_t)b * 16777216 + (size_t)(h * 64) * NTOK + (size_t)chunk * 1024;
    int tid = threadIdx.x, lane = tid & 63, wave = tid >> 6;
    int wm = wave & 1, wn = wave >> 1;
    int qd = lane >> 4, l16 = lane & 15;
    int r0 = tid >> 3, c0 = (tid & 7) * 8;
    f32x4 acc[2][2];
#pragma unroll
    for (int i = 0; i < 2; i++)
#pragma unroll
        for (int j = 0; j < 2; j++) acc[i][j] = (f32x4){0.f, 0.f, 0.f, 0.f};
#pragma unroll 1
    for (int kc = 0; kc < 1024; kc += 64) {
#pragma unroll
        for (int l = 0; l < 2; l++) {
            int row = r0 + l * 32;
            *(uint4*)&Ks[row][c0] = *(const uint4*)&kg[(size_t)row * NTOK + kc + c0];
            *(uint4*)&Qs[row][c0] = *(const uint4*)&qg[(size_t)row * NTOK + kc + c0];
        }
        __syncthreads();
#pragma unroll
        for (int kk = 0; kk < 64; kk += 32) {
            bf16x8 af[2], bfr[2];
#pragma unroll
            for (int i = 0; i < 2; i++)
                af[i] = *(const bf16x8*)&Ks[wm * 32 + i * 16 + l16][kk + qd * 8];
#pragma unroll
            for (int j = 0; j < 2; j++)
                bfr[j] = *(const bf16x8*)&Qs[wn * 32 + j * 16 + l16][kk + qd * 8];
#pragma unroll
            for (int i = 0; i < 2; i++)
#pragma unroll
                for (int j = 0; j < 2; j++)
                    acc[i][j] = __builtin_amdgcn_mfma_f32_16x16x32_bf16(af[i], bfr[j], acc[i][j], 0, 0, 0);
        }
        __syncthreads();
    }
    float* Sb = S + (size_t)(b * 16 + h) * 4096;
#pragma unroll
    for (int i = 0; i < 2; i++)
#pragma unroll
        for (int j = 0; j < 2; j++)
#pragma unroll
            for (int r = 0; r < 4; r++) {
                int d = wm * 32 + i * 16 + qd * 4 + r;
                int e = wn * 32 + j * 16 + l16;
                atomicAdd(&Sb[(size_t)d * 64 + e], acc[i][j][r]);
            }
}

// ---------------- K3: fold norms+rescale, softmax, write bf16 attn IN PLACE over S ----------------
__global__ __launch_bounds__(64) void k3_softmax(float* __restrict__ S,
                                                 const float* __restrict__ ssq,
                                                 const float* __restrict__ ssk,
                                                 const float* __restrict__ rescale) {
    int bh = blockIdx.x;  // 0..31
    int b = bh >> 4, h = bh & 15;
    int d = threadIdx.x;
    __shared__ float rq[64];
    int cbase = b * INNER + h * 64;
    rq[d] = 1.0f / fmaxf(sqrtf(ssq[cbase + d]), 1e-12f);
    float rk = 1.0f / fmaxf(sqrtf(ssk[cbase + d]), 1e-12f);
    __syncthreads();
    float rsc = rescale[h];
    const float* row = S + (size_t)bh * 4096 + (size_t)d * 64;
    float sv[64];
    float mx = -3.4e38f;
#pragma unroll
    for (int e = 0; e < 64; e++) {
        sv[e] = row[e] * rk * rq[e] * rsc;
        mx = fmaxf(mx, sv[e]);
    }
    float sum = 0.f;
#pragma unroll
    for (int e = 0; e < 64; e++) {
        sv[e] = expf(sv[e] - mx);
        sum += sv[e];
    }
    float inv = 1.0f / sum;
    __syncthreads();  // all reads of S[bh] complete before bf16 overwrite
    ushort* attn = (ushort*)((char*)S + (size_t)bh * 16384);
#pragma unroll
    for (int e = 0; e < 64; e++) attn[d * 64 + e] = f2bf(sv[e] * inv);
}

// ---------------- KT: v [b][c][t] bf16 -> vt [b][t][c] bf16 ----------------
__global__ __launch_bounds__(256) void kT_vtrans(const bf16_t* __restrict__ v,
                                                 bf16_t* __restrict__ vt) {
    __shared__ bf16_t tile[32][33];
    int b = blockIdx.z;
    const bf16_t* in = v + (size_t)b * 16777216;
    bf16_t* out = vt + (size_t)b * 16777216;
    int t0 = blockIdx.x * 32;
    int c0 = blockIdx.y * 32;
    int tx = threadIdx.x & 31, ty = threadIdx.x >> 5;
#pragma unroll
    for (int l = 0; l < 4; l++) {
        int c = c0 + ty + l * 8;
        tile[ty + l * 8][tx] = in[(size_t)c * NTOK + t0 + tx];
    }
    __syncthreads();
#pragma unroll
    for (int l = 0; l < 4; l++) {
        int t = t0 + ty + l * 8;
        out[(size_t)t * INNER + c0 + tx] = tile[tx][ty + l * 8];
    }
}

// ---------------- CVT: proj_w f32 -> bf16 ----------------
__global__ __launch_bounds__(256) void cvt_w(const float* __restrict__ w,
                                             bf16_t* __restrict__ wbf) {
    int i = (blockIdx.x * 256 + threadIdx.x) * 4;
    float4 f = *(const float4*)&w[i];
    ushort4 r;
    r.x = f2bf(f.x); r.y = f2bf(f.y); r.z = f2bf(f.z); r.w = f2bf(f.w);
    *(ushort4*)&wbf[i] = r;
}

// ---------------- K4 (MFMA): xo[d][t] = sum_e attn[d][e] * vt[t][h*64+e] ----------------
__global__ __launch_bounds__(256) void k4_mfma(const float* __restrict__ Sbase,
                                               const bf16_t* __restrict__ vt,
                                               bf16_t* __restrict__ xo) {
    int tt = blockIdx.x;  // 0..127 (128-token tiles)
    int h = blockIdx.y;   // 0..15
    int b = blockIdx.z;
    int bh = b * 16 + h;
    const ushort* attn = (const ushort*)((const char*)Sbase + (size_t)bh * 16384);
    __shared__ ushort As[64][72];
    __shared__ ushort Bs[128][72];
    int tid = threadIdx.x, lane = tid & 63, wave = tid >> 6;
    int wm = wave & 1, wn = wave >> 1;
    int qd = lane >> 4, l16 = lane & 15;
    int r0 = tid >> 3, c0 = (tid & 7) * 8;
#pragma unroll
    for (int l = 0; l < 2; l++) {
        int row = r0 + l * 32;
        *(uint4*)&As[row][c0] = *(const uint4*)&attn[row * 64 + c0];
    }
    const bf16_t* vtb = vt + (size_t)b * 16777216 + (size_t)(tt * 128) * 1024 + h * 64;
#pragma unroll
    for (int l = 0; l < 4; l++) {
        int row = r0 + l * 32;
        *(uint4*)&Bs[row][c0] = *(const uint4*)&vtb[(size_t)row * 1024 + c0];
    }
    __syncthreads();
    f32x4 acc[2][4];
#pragma unroll
    for (int i = 0; i < 2; i++)
#pragma unroll
        for (int j = 0; j < 4; j++) acc[i][j] = (f32x4){0.f, 0.f, 0.f, 0.f};
#pragma unroll
    for (int kk = 0; kk < 64; kk += 32) {
        bf16x8 af[2], bfr[4];
#pragma unroll
        for (int i = 0; i < 2; i++)
            af[i] = *(const bf16x8*)&As[wm * 32 + i * 16 + l16][kk + qd * 8];
#pragma unroll
        for (int j = 0; j < 4; j++)
            bfr[j] = *(const bf16x8*)&Bs[wn * 64 + j * 16 + l16][kk + qd * 8];
#pragma unroll
        for (int i = 0; i < 2; i++)
#pragma unroll
            for (int j = 0; j < 4; j++)
                acc[i][j] = __builtin_amdgcn_mfma_f32_16x16x32_bf16(af[i], bfr[j], acc[i][j], 0, 0, 0);
    }
    bf16_t* xob = xo + (size_t)b * 16777216 + (size_t)(h * 64) * NTOK + (size_t)tt * 128;
#pragma unroll
    for (int i = 0; i < 2; i++)
#pragma unroll
        for (int j = 0; j < 4; j++)
#pragma unroll
            for (int r = 0; r < 4; r++) {
                int d = wm * 32 + i * 16 + qd * 4 + r;
                int t = wn * 64 + j * 16 + l16;
                xob[(size_t)d * NTOK + t] = f2bf(acc[i][j][r]);
            }
}

// ---------------- GEMM-TN (MFMA): C[m][n] = sum_k A[m][k]*B[n][k] + bias ----------------
__global__ __launch_bounds__(256) void gemm_tn(
    const bf16_t* __restrict__ A, const bf16_t* __restrict__ B,
    const float* __restrict__ pb, bf16_t* __restrict__ C,
    int lda, int ldb, int ldc, int K,
    long strideA, long strideB, long strideC, int bias_on_n) {
    int mb = blockIdx.x, nb = blockIdx.y, b = blockIdx.z;
    A += (size_t)b * strideA;
    B += (size_t)b * strideB;
    C += (size_t)b * strideC;
    __shared__ ushort As[128][72];
    __shared__ ushort Bs[128][72];
    int tid = threadIdx.x;
    int lane = tid & 63, wave = tid >> 6;
    int wm = wave & 1, wn = wave >> 1;
    int q = lane >> 4, l16 = lane & 15;
    f32x4 acc[4][4];
#pragma unroll
    for (int i = 0; i < 4; i++)
#pragma unroll
        for (int j = 0; j < 4; j++) acc[i][j] = (f32x4){0.f, 0.f, 0.f, 0.f};
    const bf16_t* Ab = A + (size_t)mb * 128 * lda;
    const bf16_t* Bb = B + (size_t)nb * 128 * ldb;
    int r0 = tid >> 3;
    int c0 = (tid & 7) * 8;
#pragma unroll 1
    for (int kc = 0; kc < K; kc += 64) {
#pragma unroll
        for (int l = 0; l < 4; l++) {
            int row = l * 32 + r0;
            *(uint4*)&As[row][c0] = *(const uint4*)&Ab[(size_t)row * lda + kc + c0];
            *(uint4*)&Bs[row][c0] = *(const uint4*)&Bb[(size_t)row * ldb + kc + c0];
        }
        __syncthreads();
#pragma unroll
        for (int kk = 0; kk < 64; kk += 32) {
            bf16x8 af[4], bfr[4];
#pragma unroll
            for (int i = 0; i < 4; i++)
                af[i] = *(const bf16x8*)&As[wm * 64 + i * 16 + l16][kk + q * 8];
#pragma unroll
            for (int j = 0; j < 4; j++)
                bfr[j] = *(const bf16x8*)&Bs[wn * 64 + j * 16 + l16][kk + q * 8];
#pragma unroll
            for (int i = 0; i < 4; i++)
#pragma unroll
                for (int j = 0; j < 4; j++)
                    acc[i][j] = __builtin_amdgcn_mfma_f32_16x16x32_bf16(af[i], bfr[j], acc[i][j], 0, 0, 0);
        }
        __syncthreads();
    }
#pragma unroll
    for (int i = 0; i < 4; i++) {
#pragma unroll
        for (int j = 0; j < 4; j++) {
            int n = wn * 64 + j * 16 + l16;
            int gn = nb * 128 + n;
#pragma unroll
            for (int r = 0; r < 4; r++) {
                int m = wm * 64 + i * 16 + q * 4 + r;
                int gm = mb * 128 + m;
                float bias = bias_on_n ? pb[gn] : pb[gm];
                C[(size_t)gm * ldc + gn] = f2bf(acc[i][j][r] + bias);
            }
        }
    }
}

// ---------------- K78: fused depthwise 3x3 (GELU) -> depthwise 3x3, pe1 stays in LDS ----------------
__global__ __launch_bounds__(256) void k_pos_fused(const bf16_t* __restrict__ vp,
                                                   const float* __restrict__ w1t,
                                                   const float* __restrict__ w2t,
                                                   bf16_t* __restrict__ pe2) {
    int ychunk = blockIdx.x;  // 0..15
    int ch = blockIdx.y;      // 0..255
    int b = blockIdx.z;
    int y0 = ychunk * 8;
    __shared__ float t1[12][132];
    __shared__ float t2[10][132];
    const bf16_t* plane = vp + (size_t)b * 4194304 + (size_t)ch * NTOK;
    for (int idx = threadIdx.x; idx < 12 * 132; idx += 256) {
        int i = idx / 132, c = idx % 132;
        int gy = y0 - 2 + i, gx = c - 2;
        float val = 0.f;
        if (gy >= 0 && gy < HH && gx >= 0 && gx < WW) val = bf2f(plane[gy * WW + gx]);
        t1[i][c] = val;
    }
    float wa[9], wb[9];
#pragma unroll
    for (int t = 0; t < 9; t++) {
        wa[t] = w1t[(size_t)ch * 9 + t];
        wb[t] = w2t[(size_t)ch * 9 + t];
    }
    __syncthreads();
    // pe1 rows i=0..9 (y=y0-1+i), cols c1=0..129 (x=c1-1); zero outside image (2nd conv zero-pads pe1)
    for (int idx = threadIdx.x; idx < 10 * 130; idx += 256) {
        int i = idx / 130, c1 = idx % 130;
        int yy = y0 - 1 + i, xx = c1 - 1;
        float val = 0.f;
        if (yy >= 0 && yy < HH && xx >= 0 && xx < WW) {
            float a = wa[0] * t1[i][c1]     + wa[1] * t1[i][c1 + 1]     + wa[2] * t1[i][c1 + 2]
                    + wa[3] * t1[i + 1][c1] + wa[4] * t1[i + 1][c1 + 1] + wa[5] * t1[i + 1][c1 + 2]
                    + wa[6] * t1[i + 2][c1] + wa[7] * t1[i + 2][c1 + 1] + wa[8] * t1[i + 2][c1 + 2];
            val = 0.5f * a * (1.0f + erff(a * 0.70710678118654752f));
        }
        t2[i][c1] = val;
    }
    __syncthreads();
    int x = threadIdx.x & 127;
    int half = threadIdx.x >> 7;
    bf16_t* oplane = pe2 + (size_t)b * 4194304 + (size_t)ch * NTOK;
#pragma unroll
    for (int rp = 0; rp < 4; rp++) {
        int r = rp * 2 + half;
        float acc = wb[0] * t2[r][x]     + wb[1] * t2[r][x + 1]     + wb[2] * t2[r][x + 2]
                  + wb[3] * t2[r + 1][x] + wb[4] * t2[r + 1][x + 1] + wb[5] * t2[r + 1][x + 2]
                  + wb[6] * t2[r + 2][x] + wb[7] * t2[r + 2][x + 1] + wb[8] * t2[r + 2][x + 2];
        oplane[(size_t)(y0 + r) * WW + x] = f2bf(acc);
    }
}

// ---------------- K9: out[t][c] = outc[t][c] + pe2[c][t]  -> f32 output ----------------
__global__ __launch_bounds__(256) void k9_final(const bf16_t* __restrict__ outc,
                                                const bf16_t* __restrict__ pe2,
                                                float* __restrict__ out) {
    __shared__ float tile[32][33];
    int t0 = blockIdx.x * 32;
    int c0 = blockIdx.y * 32;
    int b = blockIdx.z;
    int tx = threadIdx.x & 31, ty = threadIdx.x >> 5;
    const bf16_t* peb = pe2 + (size_t)b * 4194304;
    const bf16_t* ob = outc + (size_t)b * 4194304;
    float* o = out + (size_t)b * 4194304;
#pragma unroll
    for (int l = 0; l < 4; l++) {
        int c = c0 + ty + l * 8;
        tile[ty + l * 8][tx] = bf2f(peb[(size_t)c * NTOK + t0 + tx]);
    }
    __syncthreads();
#pragma unroll
    for (int l = 0; l < 4; l++) {
        int t = t0 + ty + l * 8;
        size_t idx = (size_t)t * CDIM + c0 + tx;
        o[idx] = bf2f(ob[idx]) + tile[tx][ty + l * 8];
    }
}

extern "C" void kernel_launch(void* const* d_in, const int* in_sizes, int n_in,
                              void* d_out, int out_size, void* d_ws, size_t ws_size,
                              hipStream_t stream) {
    const float* x_in    = (const float*)d_in[0];
    const float* wq      = (const float*)d_in[1];
    const float* wk      = (const float*)d_in[2];
    const float* wv      = (const float*)d_in[3];
    const float* qg      = (const float*)d_in[4];
    const float* qb      = (const float*)d_in[5];
    const float* qm      = (const float*)d_in[6];
    const float* qv      = (const float*)d_in[7];
    const float* kg      = (const float*)d_in[8];
    const float* kb      = (const float*)d_in[9];
    const float* km      = (const float*)d_in[10];
    const float* kv_     = (const float*)d_in[11];
    const float* vg      = (const float*)d_in[12];
    const float* vb      = (const float*)d_in[13];
    const float* vm      = (const float*)d_in[14];
    const float* vv      = (const float*)d_in[15];
    const float* rescale = (const float*)d_in[16];
    const float* proj_w  = (const float*)d_in[17];
    const float* proj_b  = (const float*)d_in[18];
    const float* pos_w1  = (const float*)d_in[19];
    const float* pos_w2  = (const float*)d_in[20];

    char* ws = (char*)d_ws;
    bf16_t* xn   = (bf16_t*)(ws + OFF_XN);
    bf16_t* q    = (bf16_t*)(ws + OFF_Q);
    bf16_t* k    = (bf16_t*)(ws + OFF_K);
    bf16_t* v    = (bf16_t*)(ws + OFF_V);
    bf16_t* vt   = (bf16_t*)(ws + OFF_VT);
    bf16_t* xo   = (bf16_t*)(ws + OFF_XO);
    bf16_t* outc = (bf16_t*)(ws + OFF_OUTC);
    bf16_t* vp   = (bf16_t*)(ws + OFF_VP);
    bf16_t* pe2  = (bf16_t*)(ws + OFF_PE2);
    bf16_t* wbf  = (bf16_t*)(ws + OFF_WBF);
    float* S     = (float*)(ws + OFF_S);
    float* ssq   = (float*)(ws + OFF_SSQ);
    float* ssk   = (float*)(ws + OFF_SSK);

    hipMemsetAsync(ws + OFF_S, 0, (size_t)540672, stream);

    k0_transpose<<<dim3(512, 8, 2), 256, 0, stream>>>(x_in, xn);
    k1_qkv<<<dim3(16, 256, 2), 256, 0, stream>>>(xn, wq, wk, wv,
                                                 qg, qb, qm, qv,
                                                 kg, kb, km, kv_,
                                                 vg, vb, vm, vv,
                                                 q, k, v, ssq, ssk);
    k2_mfma<<<dim3(16, 16, 2), 256, 0, stream>>>(q, k, S);
    k3_softmax<<<dim3(32), 64, 0, stream>>>(S, ssq, ssk, rescale);
    kT_vtrans<<<dim3(512, 32, 2), 256, 0, stream>>>(v, vt);   // q dead -> vt in B
    cvt_w<<<dim3(256), 256, 0, stream>>>(proj_w, wbf);        // v dead -> wbf in D tail
    k4_mfma<<<dim3(128, 16, 2), 256, 0, stream>>>(S, vt, xo); // k dead -> xo in C
    // k5: outc[t][co] = xo_flat[t][:] . W[co][:]   (M=16384,N=256,K=1024)
    gemm_tn<<<dim3(128, 2, 2), 256, 0, stream>>>(xo, wbf, proj_b, outc,
                                                 1024, 1024, 256, 1024,
                                                 16777216L, 0L, 4194304L, 1);
    // k6: vp[co][t] = W[co][:] . vt[t][:]          (M=256,N=16384,K=1024)
    gemm_tn<<<dim3(2, 128, 2), 256, 0, stream>>>(wbf, vt, proj_b, vp,
                                                 1024, 1024, 16384, 1024,
                                                 0L, 16777216L, 4194304L, 0);
    k_pos_fused<<<dim3(16, 256, 2), 256, 0, stream>>>(vp, pos_w1, pos_w2, pe2);
    k9_final<<<dim3(512, 8, 2), 256, 0, stream>>>(outc, pe2, (float*)d_out);
}